// Round 1
// baseline (622.913 us; speedup 1.0000x reference)
//
#include <hip/hip_runtime.h>

typedef unsigned short u16;
typedef __attribute__((ext_vector_type(8))) short short8;   // 8 bf16 = 4 VGPRs (MFMA A/B frag)
typedef __attribute__((ext_vector_type(4))) float floatx4;  // MFMA C/D frag

__device__ __forceinline__ u16 f2bf(float f) {
    union { float f; unsigned int u; } v;
    v.f = f;
    unsigned int u = v.u;
    return (u16)((u + 0x7FFFu + ((u >> 16) & 1u)) >> 16);  // RNE
}

__device__ __forceinline__ void cvt8_f32_bf16(const float* __restrict__ p, u16* dst) {
    const float4 x = *(const float4*)p;
    const float4 y = *(const float4*)(p + 4);
    short8 s;
    s[0] = (short)f2bf(x.x); s[1] = (short)f2bf(x.y);
    s[2] = (short)f2bf(x.z); s[3] = (short)f2bf(x.w);
    s[4] = (short)f2bf(y.x); s[5] = (short)f2bf(y.y);
    s[6] = (short)f2bf(y.z); s[7] = (short)f2bf(y.w);
    *(short8*)dst = s;
}

// async global->LDS DMA, 16B per lane. LDS dest wave-uniform base + lane*16.
__device__ __forceinline__ void gld_lds16(const u16* g, u16* l) {
    __builtin_amdgcn_global_load_lds(
        (const __attribute__((address_space(1))) void*)g,
        (__attribute__((address_space(3))) void*)l,
        16, 0, 0);
}

// ---------------------------------------------------------------------------
// Pre-pass: convert the three fp32 inputs to bf16 in workspace.
// ---------------------------------------------------------------------------
__global__ __launch_bounds__(256) void cvt3_kernel(
    const float* __restrict__ a, u16* __restrict__ oa, long na,
    const float* __restrict__ b, u16* __restrict__ ob, long nb,
    const float* __restrict__ c, u16* __restrict__ oc, long nc) {
    const float* in; u16* out; long n;
    if (blockIdx.y == 0)      { in = a; out = oa; n = na; }
    else if (blockIdx.y == 1) { in = b; out = ob; n = nb; }
    else                      { in = c; out = oc; n = nc; }
    const long i = ((long)blockIdx.x * 256 + threadIdx.x) * 8;
    if (i >= n) return;
    cvt8_f32_bf16(in + i, out + i);
}

// ===========================================================================
// 256x256 8-phase GEMM (T2+T3+T4+T5 per the measured template).
//   BM=BN=256, BK=64, 512 threads = 8 waves (2M x 4N), per-wave 128x64 out.
//   LDS: 2 dbuf x (A 256x64 + B 256x64) bf16 = 128 KiB.
//   LDS layout: row-major [256][64] bf16 with 16B-slot XOR swizzle
//   slot_phys = slot_log ^ (row&7). global_load_lds writes linearly, so the
//   per-lane GLOBAL source column is pre-swizzled (rule 21, m173 pattern);
//   ds_reads apply the same XOR. 4 phases per K-tile, counted vmcnt(4) once
//   per K-tile (2 half-tiles = 4 loads stay in flight), never 0 in the loop.
//   Staging issue schedule (tile j, phases 0..3):
//     p0: A-half0(j+1) -> buf (j+1)&1     (A[1-cur] rows fully read in j-1 p3)
//     p1: A-half1(j+1) -> buf (j+1)&1
//     p2: B-half0(j+2) -> buf  j&1        (B[cur] fully read in p0 of j)
//     p3: B-half1(j+2) -> buf  j&1, then vmcnt(4): waits A(j+1), leaves B(j+2).
// ===========================================================================

#define GEMM8P_PROLOGUE()                                                      \
    const int t    = threadIdx.x;                                              \
    const int w    = t >> 6;                                                   \
    const int lane = t & 63;                                                   \
    const int quad = lane >> 4;                                                \
    const int l16  = lane & 15;                                                \
    const int sw   = lane & 7;                                                 \
    const int nwg  = gridDim.x;                                                \
    const int qq = nwg >> 3, rr = nwg & 7;                                     \
    const int xcd = blockIdx.x & 7, idx = blockIdx.x >> 3;                     \
    const int wgid = (xcd < rr ? xcd * (qq + 1)                                \
                               : rr * (qq + 1) + (xcd - rr) * qq) + idx;       \
    const int m0 = (wgid / nt) * 256;                                          \
    const int n0 = (wgid % nt) * 256;                                          \
    const int wm = (w >> 2) * 128;                                             \
    const int wn = (w & 3) * 64;                                               \
    const int trow = t >> 3;                                                   \
    const int scol = ((t & 7) ^ (trow & 7)) * 8;                               \
    const long Kl = K;                                                         \
    const u16* Asrc = A + (long)(m0 + trow) * Kl + scol;                       \
    auto stageA = [&](int jt, int h, int b) {                                  \
        _Pragma("unroll")                                                      \
        for (int i = 0; i < 2; i++) {                                          \
            const u16* src = Asrc + (long)(h * 128 + i * 64) * Kl + (long)jt * 64; \
            u16* dst = &aLds[b][0] + h * 8192 + i * 4096 + t * 8;              \
            gld_lds16(src, dst);                                               \
        }                                                                      \
    };                                                                         \
    auto stageB = [&](int jt, int h, int b) {                                  \
        _Pragma("unroll")                                                      \
        for (int i = 0; i < 2; i++) {                                          \
            int rb = n0 + h * 128 + i * 64 + trow;                             \
            if (rb > N - 1) rb = N - 1;                                        \
            const u16* src = B + (long)rb * Kl + scol + (long)jt * 64;         \
            u16* dst = &bLds[b][0] + h * 8192 + i * 4096 + t * 8;              \
            gld_lds16(src, dst);                                               \
        }                                                                      \
    };                                                                         \
    floatx4 acc[8][4];                                                         \
    const floatx4 zf4 = {0.f, 0.f, 0.f, 0.f};                                  \
    _Pragma("unroll")                                                          \
    for (int i = 0; i < 8; i++)                                                \
        _Pragma("unroll")                                                      \
        for (int j = 0; j < 4; j++) acc[i][j] = zf4;                           \
    /* prologue: K-tile 0 fully + B halves of K-tile 1 */                      \
    stageA(0, 0, 0); stageA(0, 1, 0);                                          \
    stageB(0, 0, 0); stageB(0, 1, 0);                                          \
    stageB(1, 0, 1); stageB(1, 1, 1);                                          \
    asm volatile("s_waitcnt vmcnt(4)" ::: "memory");                           \
    __builtin_amdgcn_s_barrier();

#define GPHASE(P, STAGE_STMT, TAIL_VM)                                         \
    {                                                                          \
        short8 afA[2], afB[2];                                                 \
        _Pragma("unroll")                                                      \
        for (int ks = 0; ks < 2; ks++) {                                       \
            afA[ks] = *(const short8*)(Ac + (wm + (2 * (P)) * 16 + l16) * 64   \
                                          + ((4 * ks + quad) ^ sw) * 8);       \
            afB[ks] = *(const short8*)(Ac + (wm + (2 * (P) + 1) * 16 + l16) * 64 \
                                          + ((4 * ks + quad) ^ sw) * 8);       \
        }                                                                      \
        STAGE_STMT;                                                            \
        __builtin_amdgcn_s_barrier();                                          \
        asm volatile("s_waitcnt lgkmcnt(0)" ::: "memory");                     \
        __builtin_amdgcn_sched_barrier(0);                                     \
        __builtin_amdgcn_s_setprio(1);                                         \
        _Pragma("unroll")                                                      \
        for (int ks = 0; ks < 2; ks++) {                                       \
            _Pragma("unroll")                                                  \
            for (int ni = 0; ni < 4; ni++) {                                   \
                acc[2 * (P)][ni] = __builtin_amdgcn_mfma_f32_16x16x32_bf16(    \
                    afA[ks], bf[ni][ks], acc[2 * (P)][ni], 0, 0, 0);           \
                acc[2 * (P) + 1][ni] = __builtin_amdgcn_mfma_f32_16x16x32_bf16(\
                    afB[ks], bf[ni][ks], acc[2 * (P) + 1][ni], 0, 0, 0);       \
            }                                                                  \
        }                                                                      \
        __builtin_amdgcn_s_setprio(0);                                         \
        TAIL_VM;                                                               \
        __builtin_amdgcn_s_barrier();                                          \
    }

#define GEMM8P_KLOOP()                                                         \
    const int JT = K >> 6;                                                     \
    for (int j = 0; j < JT; ++j) {                                             \
        const int cur = j & 1;                                                 \
        const int nb  = cur ^ 1;                                               \
        const int jn1 = (j + 1 < JT) ? j + 1 : JT - 1;                         \
        const int jn2 = (j + 2 < JT) ? j + 2 : JT - 1;                         \
        const u16* Ac = &aLds[cur][0];                                         \
        const u16* Bc = &bLds[cur][0];                                         \
        short8 bf[4][2];                                                       \
        _Pragma("unroll")                                                      \
        for (int ni = 0; ni < 4; ni++)                                         \
            _Pragma("unroll")                                                  \
            for (int ks = 0; ks < 2; ks++)                                     \
                bf[ni][ks] = *(const short8*)(Bc + (wn + ni * 16 + l16) * 64   \
                                                 + ((4 * ks + quad) ^ sw) * 8);\
        GPHASE(0, stageA(jn1, 0, nb), );                                       \
        GPHASE(1, stageA(jn1, 1, nb), );                                       \
        GPHASE(2, stageB(jn2, 0, cur), );                                      \
        GPHASE(3, stageB(jn2, 1, cur),                                         \
               asm volatile("s_waitcnt vmcnt(4)" ::: "memory"));               \
    }                                                                          \
    asm volatile("s_waitcnt vmcnt(0)" ::: "memory");

// ---------------------------------------------------------------------------
// QKV projection, 8-phase, fused RoPE epilogue. Writes q[n][h][l][64]
// (x0.125 folded), k[n][l][64], V transposed vt[n][d][l].
// ---------------------------------------------------------------------------
__global__ __launch_bounds__(512, 2) void gemm_qkv_8p(
    const u16* __restrict__ A, const u16* __restrict__ B,
    u16* __restrict__ qb, u16* __restrict__ kb, u16* __restrict__ vt,
    int M, int N, int K, int nt) {
    __shared__ __align__(16) u16 aLds[2][256 * 64];
    __shared__ __align__(16) u16 bLds[2][256 * 64];
    GEMM8P_PROLOGUE()
    GEMM8P_KLOOP()

    // ---- fused RoPE epilogue (C/D: col=l16, row=quad*4+r) ----
#pragma unroll
    for (int ni = 0; ni < 4; ni++) {
        const int c = n0 + wn + ni * 16 + l16;
        if (c >= N) continue;
        const int hh = c >> 6;
        const int d  = c & 63;
        float inv = 0.f;
        if (hh < 72) inv = expf((float)(2 * (d & 31)) * (-0.14391156831212787f));
#pragma unroll
        for (int mi = 0; mi < 8; mi++) {
#pragma unroll
            for (int r = 0; r < 4; r++) {
                const int row = m0 + wm + mi * 16 + quad * 4 + r;   // token
                const int tn = row >> 10;
                const int tl = row & 1023;
                float val = acc[mi][ni][r];
                if (hh < 72) {
                    float sv, cv;
                    sincosf((float)tl * inv, &sv, &cv);
                    const float pacc = acc[mi][ni ^ 2][r];          // col c^32
                    val = val * cv + ((d < 32) ? -pacc : pacc) * sv;
                }
                if (hh < 71) {
                    qb[((long)((tn * 71 + hh) * 1024 + tl)) * 64 + d] = f2bf(val * 0.125f);
                } else if (hh == 71) {
                    kb[((long)(tn * 1024 + tl)) * 64 + d] = f2bf(val);
                } else {
                    vt[((long)(tn * 64 + d)) * 1024 + tl] = f2bf(val);  // V^T
                }
            }
        }
    }
}

// ---------------------------------------------------------------------------
// Dense projection, 8-phase: C_fp32[M,N] = A_bf16[M,K]*B_bf16[N,K]^T.
// ---------------------------------------------------------------------------
__global__ __launch_bounds__(512, 2) void gemm_dense_8p(
    const u16* __restrict__ A, const u16* __restrict__ B,
    float* __restrict__ C, int M, int N, int K, int nt) {
    __shared__ __align__(16) u16 aLds[2][256 * 64];
    __shared__ __align__(16) u16 bLds[2][256 * 64];
    GEMM8P_PROLOGUE()
    GEMM8P_KLOOP()

#pragma unroll
    for (int ni = 0; ni < 4; ni++) {
        const int col = n0 + wn + ni * 16 + l16;
        if (col >= N) continue;
#pragma unroll
        for (int mi = 0; mi < 8; mi++) {
#pragma unroll
            for (int r = 0; r < 4; r++) {
                const int row = m0 + wm + mi * 16 + quad * 4 + r;
                C[(long)row * N + col] = acc[mi][ni][r];
            }
        }
    }
}

// ---------------------------------------------------------------------------
// Flash-style MQA causal attention v2 (unchanged this round).
// ---------------------------------------------------------------------------
__global__ __launch_bounds__(256) void attn_kernel2(const u16* __restrict__ qb,
                                                    const u16* __restrict__ kb,
                                                    const u16* __restrict__ vt,
                                                    u16* __restrict__ ao) {
    __shared__ __align__(16) u16 k_lds[2][64 * 72];
    __shared__ __align__(16) u16 v_lds[2][64 * 72];
    __shared__ __align__(16) u16 p_lds[4][16 * 72];
    const int qt2 = blockIdx.x;
    const int h   = blockIdx.y;
    const int n   = blockIdx.z;
    const int t    = threadIdx.x;
    const int w    = t >> 6;
    const int lane = t & 63;
    const int quad = lane >> 4;
    const int l16  = lane & 15;
    const int Q0 = qt2 * 128;

    short8 aq[2][2];
#pragma unroll
    for (int mf = 0; mf < 2; mf++) {
        const u16* qrow = qb +
            ((long)((n * 71 + h) * 1024 + Q0 + 64 * mf + w * 16 + l16)) * 64;
        aq[mf][0] = *(const short8*)(qrow + quad * 8);
        aq[mf][1] = *(const short8*)(qrow + 32 + quad * 8);
    }

    floatx4 o[2][4];
    float lst[2][4];
    const floatx4 zf4 = {0.f, 0.f, 0.f, 0.f};
#pragma unroll
    for (int mf = 0; mf < 2; mf++) {
#pragma unroll
        for (int i = 0; i < 4; i++) { o[mf][i] = zf4; lst[mf][i] = 0.f; }
    }

    const int srow = t >> 2;
    const int scol = (t & 3) * 16;
    const u16* kb_n = kb + (long)n * 1024 * 64;
    const u16* vt_n = vt + (long)n * 64 * 1024;
    u16* pw = p_lds[w];

    const int ktend = 2 * qt2 + 2;

    auto stage = [&](int kt, int b) {
        const u16* krow = kb_n + (long)(kt * 64 + srow) * 64 + scol;
        *(uint4*)(k_lds[b] + srow * 72 + scol)     = *(const uint4*)(krow);
        *(uint4*)(k_lds[b] + srow * 72 + scol + 8) = *(const uint4*)(krow + 8);
        const u16* vrow = vt_n + (long)srow * 1024 + kt * 64 + scol;
        *(uint4*)(v_lds[b] + srow * 72 + scol)     = *(const uint4*)(vrow);
        *(uint4*)(v_lds[b] + srow * 72 + scol + 8) = *(const uint4*)(vrow + 8);
    };

    stage(0, 0);
    for (int kt = 0; kt < ktend; kt++) {
        const int buf = kt & 1;
        __syncthreads();
        if (kt + 1 < ktend) stage(kt + 1, 1 - buf);

#pragma unroll
        for (int mf = 0; mf < 2; mf++) {
            if (mf == 0 && kt == 2 * qt2 + 1) continue;
            floatx4 s[4];
#pragma unroll
            for (int sub = 0; sub < 4; sub++) {
                const short8 b0 = *(const short8*)(k_lds[buf] + (sub * 16 + l16) * 72 + quad * 8);
                const short8 b1 = *(const short8*)(k_lds[buf] + (sub * 16 + l16) * 72 + 32 + quad * 8);
                floatx4 z = zf4;
                z = __builtin_amdgcn_mfma_f32_16x16x32_bf16(aq[mf][0], b0, z, 0, 0, 0);
                z = __builtin_amdgcn_mfma_f32_16x16x32_bf16(aq[mf][1], b1, z, 0, 0, 0);
                s[sub] = z;
            }
            const bool diag = (kt == 2 * qt2 + mf);
            const int rowb = Q0 + 64 * mf + w * 16 + quad * 4;
#pragma unroll
            for (int sub = 0; sub < 4; sub++) {
                const int key = kt * 64 + sub * 16 + l16;
#pragma unroll
                for (int r = 0; r < 4; r++) {
                    float p = __expf(s[sub][r]);
                    if (diag && key > rowb + r) p = 0.f;
                    lst[mf][r] += p;
                    pw[(quad * 4 + r) * 72 + sub * 16 + l16] = f2bf(p);
                }
            }
            const short8 ap0 = *(const short8*)(pw + l16 * 72 + quad * 8);
            const short8 ap1 = *(const short8*)(pw + l16 * 72 + 32 + quad * 8);
#pragma unroll
            for (int dch = 0; dch < 4; dch++) {
                const short8 bv0 = *(const short8*)(v_lds[buf] + (dch * 16 + l16) * 72 + quad * 8);
                const short8 bv1 = *(const short8*)(v_lds[buf] + (dch * 16 + l16) * 72 + 32 + quad * 8);
                o[mf][dch] = __builtin_amdgcn_mfma_f32_16x16x32_bf16(ap0, bv0, o[mf][dch], 0, 0, 0);
                o[mf][dch] = __builtin_amdgcn_mfma_f32_16x16x32_bf16(ap1, bv1, o[mf][dch], 0, 0, 0);
            }
        }
    }

    float lsum[2][4];
#pragma unroll
    for (int mf = 0; mf < 2; mf++) {
#pragma unroll
        for (int r = 0; r < 4; r++) {
            float v = lst[mf][r];
#pragma unroll
            for (int mk = 1; mk < 16; mk <<= 1) v += __shfl_xor(v, mk, 64);
            lsum[mf][r] = v;
        }
    }
#pragma unroll
    for (int mf = 0; mf < 2; mf++) {
#pragma unroll
        for (int dch = 0; dch < 4; dch++) {
#pragma unroll
            for (int r = 0; r < 4; r++) {
                const float val = o[mf][dch][r] / lsum[mf][r];
                const int row = n * 1024 + Q0 + 64 * mf + w * 16 + quad * 4 + r;
                const int col = h * 64 + dch * 16 + l16;
                ao[(long)row * 4544 + col] = f2bf(val);
            }
        }
    }
}

// ---------------------------------------------------------------------------
// Fallback path kernels (fp32 staging) — used only if ws too small.
// ---------------------------------------------------------------------------
__global__ __launch_bounds__(256) void gemm_qkv_f32(const float* __restrict__ A,
                                                    const float* __restrict__ B,
                                                    u16* __restrict__ qb,
                                                    u16* __restrict__ kb,
                                                    u16* __restrict__ vt,
                                                    int M, int N, int K) {
    __shared__ __align__(16) u16 a_lds[128 * 32];
    __shared__ __align__(16) u16 b_lds[128 * 32];
    const int t    = threadIdx.x;
    const int lane = t & 63;
    const int w    = t >> 6;
    const int quad = lane >> 4;
    const int l16  = lane & 15;
    const int m0 = blockIdx.y * 128;
    const int n0 = blockIdx.x * 128;
    const int wm = (w >> 1) * 64;
    const int wn = (w & 1) * 64;
    const int srow = t >> 2;
    const int scol = (t & 3) * 8;
    const float* Ap0 = A + (long)(m0 + srow) * K + scol;
    const float* Ap1 = A + (long)(m0 + 64 + srow) * K + scol;
    int bn0 = n0 + srow;      if (bn0 >= N) bn0 = N - 1;
    int bn1 = n0 + 64 + srow; if (bn1 >= N) bn1 = N - 1;
    const float* Bp0 = B + (long)bn0 * K + scol;
    const float* Bp1 = B + (long)bn1 * K + scol;
    u16* as0 = a_lds + srow * 32 + scol;
    u16* as1 = a_lds + (64 + srow) * 32 + scol;
    u16* bs0 = b_lds + srow * 32 + scol;
    u16* bs1 = b_lds + (64 + srow) * 32 + scol;
    floatx4 acc[4][4];
    const floatx4 zf4 = {0.f, 0.f, 0.f, 0.f};
#pragma unroll
    for (int i = 0; i < 4; i++)
#pragma unroll
        for (int j = 0; j < 4; j++) acc[i][j] = zf4;
    for (int k0 = 0; k0 < K; k0 += 32) {
        cvt8_f32_bf16(Ap0 + k0, as0);
        cvt8_f32_bf16(Ap1 + k0, as1);
        cvt8_f32_bf16(Bp0 + k0, bs0);
        cvt8_f32_bf16(Bp1 + k0, bs1);
        __syncthreads();
        short8 af[4], bfr[4];
#pragma unroll
        for (int i = 0; i < 4; i++)
            af[i] = *(const short8*)(a_lds + (wm + i * 16 + l16) * 32 + quad * 8);
#pragma unroll
        for (int j = 0; j < 4; j++)
            bfr[j] = *(const short8*)(b_lds + (wn + j * 16 + l16) * 32 + quad * 8);
#pragma unroll
        for (int i = 0; i < 4; i++)
#pragma unroll
            for (int j = 0; j < 4; j++)
                acc[i][j] = __builtin_amdgcn_mfma_f32_16x16x32_bf16(af[i], bfr[j], acc[i][j], 0, 0, 0);
        __syncthreads();
    }
#pragma unroll
    for (int j = 0; j < 4; j++) {
        const int c = n0 + wn + j * 16 + l16;
        if (c >= N) continue;
        const int hh = c >> 6;
        const int d  = c & 63;
        float inv = 0.f;
        if (hh < 72) inv = expf((float)(2 * (d & 31)) * (-0.14391156831212787f));
#pragma unroll
        for (int i = 0; i < 4; i++) {
#pragma unroll
            for (int r = 0; r < 4; r++) {
                const int row = m0 + wm + i * 16 + quad * 4 + r;
                const int tn = row >> 10;
                const int tl = row & 1023;
                float val = acc[i][j][r];
                if (hh < 72) {
                    float sv, cv;
                    sincosf((float)tl * inv, &sv, &cv);
                    const float pacc = acc[i][j ^ 2][r];
                    val = val * cv + ((d < 32) ? -pacc : pacc) * sv;
                }
                if (hh < 71) {
                    qb[((long)((tn * 71 + hh) * 1024 + tl)) * 64 + d] = f2bf(val * 0.125f);
                } else if (hh == 71) {
                    kb[((long)(tn * 1024 + tl)) * 64 + d] = f2bf(val);
                } else {
                    vt[((long)(tn * 64 + d)) * 1024 + tl] = f2bf(val);
                }
            }
        }
    }
}

__global__ __launch_bounds__(256) void gemm_dense_f32(const u16* __restrict__ A,
                                                      const float* __restrict__ B,
                                                      float* __restrict__ C,
                                                      int M, int N, int K) {
    __shared__ __align__(16) u16 a_lds[128 * 32];
    __shared__ __align__(16) u16 b_lds[128 * 32];
    const int t    = threadIdx.x;
    const int lane = t & 63;
    const int w    = t >> 6;
    const int quad = lane >> 4;
    const int l16  = lane & 15;
    const int m0 = blockIdx.y * 128;
    const int n0 = blockIdx.x * 128;
    const int wm = (w >> 1) * 64;
    const int wn = (w & 1) * 64;
    const int srow = t >> 2;
    const int scol = (t & 3) * 8;
    const u16* Ap0 = A + (long)(m0 + srow) * K + scol;
    const u16* Ap1 = A + (long)(m0 + 64 + srow) * K + scol;
    int bn0 = n0 + srow;      if (bn0 >= N) bn0 = N - 1;
    int bn1 = n0 + 64 + srow; if (bn1 >= N) bn1 = N - 1;
    const float* Bp0 = B + (long)bn0 * K + scol;
    const float* Bp1 = B + (long)bn1 * K + scol;
    u16* as0 = a_lds + srow * 32 + scol;
    u16* as1 = a_lds + (64 + srow) * 32 + scol;
    u16* bs0 = b_lds + srow * 32 + scol;
    u16* bs1 = b_lds + (64 + srow) * 32 + scol;
    floatx4 acc[4][4];
    const floatx4 zf4 = {0.f, 0.f, 0.f, 0.f};
#pragma unroll
    for (int i = 0; i < 4; i++)
#pragma unroll
        for (int j = 0; j < 4; j++) acc[i][j] = zf4;
    for (int k0 = 0; k0 < K; k0 += 32) {
        *(uint4*)as0 = *(const uint4*)(Ap0 + k0);
        *(uint4*)as1 = *(const uint4*)(Ap1 + k0);
        cvt8_f32_bf16(Bp0 + k0, bs0);
        cvt8_f32_bf16(Bp1 + k0, bs1);
        __syncthreads();
        short8 af[4], bfr[4];
#pragma unroll
        for (int i = 0; i < 4; i++)
            af[i] = *(const short8*)(a_lds + (wm + i * 16 + l16) * 32 + quad * 8);
#pragma unroll
        for (int j = 0; j < 4; j++)
            bfr[j] = *(const short8*)(b_lds + (wn + j * 16 + l16) * 32 + quad * 8);
#pragma unroll
        for (int i = 0; i < 4; i++)
#pragma unroll
            for (int j = 0; j < 4; j++)
                acc[i][j] = __builtin_amdgcn_mfma_f32_16x16x32_bf16(af[i], bfr[j], acc[i][j], 0, 0, 0);
        __syncthreads();
    }
#pragma unroll
    for (int i = 0; i < 4; i++) {
#pragma unroll
        for (int j = 0; j < 4; j++) {
            const int col = n0 + wn + j * 16 + l16;
            if (col < N) {
#pragma unroll
                for (int r = 0; r < 4; r++) {
                    const int row = m0 + wm + i * 16 + quad * 4 + r;
                    C[(long)row * N + col] = acc[i][j][r];
                }
            }
        }
    }
}

// ---------------------------------------------------------------------------
extern "C" void kernel_launch(void* const* d_in, const int* in_sizes, int n_in,
                              void* d_out, int out_size, void* d_ws, size_t ws_size,
                              hipStream_t stream) {
    (void)in_sizes; (void)n_in; (void)out_size;
    const float* hidden  = (const float*)d_in[0];   // (2,1024,4544) fp32
    const float* w_qkv   = (const float*)d_in[1];   // (4672,4544)  fp32
    const float* w_dense = (const float*)d_in[2];   // (4544,4544)  fp32
    float* out = (float*)d_out;                     // (2,1024,4544) fp32

    const long N_HID = (long)2048 * 4544;
    const long N_QKV = (long)4672 * 4544;
    const long N_DEN = (long)4544 * 4544;
    const long N_Q   = (long)2 * 71 * 1024 * 64;
    const long N_KV  = (long)2 * 1024 * 64;
    const long N_AO  = (long)2048 * 4544;

    const size_t needA = (size_t)(N_HID + N_QKV + N_DEN + N_Q + 2 * N_KV + N_AO) * 2;

    if (ws_size >= needA) {
        // ---- Path A: bf16 pre-convert + 8-phase 256^2 GEMMs ----
        u16* hid_bf  = (u16*)d_ws;
        u16* wqkv_bf = hid_bf + N_HID;
        u16* wden_bf = wqkv_bf + N_QKV;
        u16* qbuf    = wden_bf + N_DEN;
        u16* kbuf    = qbuf + N_Q;
        u16* vtbuf   = kbuf + N_KV;    // V^T: [n][64][1024]
        u16* aout    = vtbuf + N_KV;

        cvt3_kernel<<<dim3(10366, 3), 256, 0, stream>>>(
            hidden, hid_bf, N_HID, w_qkv, wqkv_bf, N_QKV, w_dense, wden_bf, N_DEN);
        // M=2048 (8 tiles), N=4672 (19 tiles), K=4544 (71 K-tiles)
        gemm_qkv_8p<<<dim3(8 * 19), 512, 0, stream>>>(hid_bf, wqkv_bf,
                                                      qbuf, kbuf, vtbuf,
                                                      2048, 4672, 4544, 19);
        attn_kernel2<<<dim3(8, 71, 2), 256, 0, stream>>>(qbuf, kbuf, vtbuf, aout);
        // M=2048 (8 tiles), N=4544 (18 tiles)
        gemm_dense_8p<<<dim3(8 * 18), 512, 0, stream>>>(aout, wden_bf, out,
                                                        2048, 4544, 4544, 18);
    } else {
        // ---- Path B: fallback (fp32 staging conversion) ----
        u16* qbuf  = (u16*)d_ws;
        u16* kbuf  = qbuf + N_Q;
        u16* vtbuf = kbuf + N_KV;
        u16* aout  = vtbuf + N_KV;
        gemm_qkv_f32<<<dim3(37, 16), 256, 0, stream>>>(hidden, w_qkv,
                                                       qbuf, kbuf, vtbuf,
                                                       2048, 4672, 4544);
        attn_kernel2<<<dim3(8, 71, 2), 256, 0, stream>>>(qbuf, kbuf, vtbuf, aout);
        gemm_dense_f32<<<dim3(36, 16), 256, 0, stream>>>(aout, w_dense, out,
                                                         2048, 4544, 4544);
    }
}

// Round 3
// 537.210 us; speedup vs baseline: 1.1595x; 1.1595x over previous
//
#include <hip/hip_runtime.h>

typedef unsigned short u16;
typedef __attribute__((ext_vector_type(8))) short short8;   // 8 bf16 = 4 VGPRs (MFMA A/B frag)
typedef __attribute__((ext_vector_type(4))) float floatx4;  // MFMA C/D frag

__device__ __forceinline__ u16 f2bf(float f) {
    union { float f; unsigned int u; } v;
    v.f = f;
    unsigned int u = v.u;
    return (u16)((u + 0x7FFFu + ((u >> 16) & 1u)) >> 16);  // RNE
}

__device__ __forceinline__ void cvt8_f32_bf16(const float* __restrict__ p, u16* dst) {
    const float4 x = *(const float4*)p;
    const float4 y = *(const float4*)(p + 4);
    short8 s;
    s[0] = (short)f2bf(x.x); s[1] = (short)f2bf(x.y);
    s[2] = (short)f2bf(x.z); s[3] = (short)f2bf(x.w);
    s[4] = (short)f2bf(y.x); s[5] = (short)f2bf(y.y);
    s[6] = (short)f2bf(y.z); s[7] = (short)f2bf(y.w);
    *(short8*)dst = s;
}

// async global->LDS DMA, 16B per lane. LDS dest wave-uniform base + lane*16.
__device__ __forceinline__ void gld_lds16(const u16* g, u16* l) {
    __builtin_amdgcn_global_load_lds(
        (const __attribute__((address_space(1))) void*)g,
        (__attribute__((address_space(3))) void*)l,
        16, 0, 0);
}

// Inline-asm ds_read_b128: INVISIBLE to SIInsertWaitcnts, so the compiler
// cannot insert conservative vmcnt(0) drains ordering it against outstanding
// global_load_lds DMA (the R1 per-phase stall). We own all waits manually:
// s_waitcnt lgkmcnt(0) + sched_barrier(0) before the MFMAs (rule 18),
// counted vmcnt once per K-tile. Generic LDS pointer truncation to 32 bit is
// valid: shared aperture is 4 GiB-aligned, low 32 bits = LDS byte offset.
#define DSR(dst, ptr)                                                          \
    asm volatile("ds_read_b128 %0, %1"                                         \
                 : "=v"(dst)                                                   \
                 : "v"((unsigned)(unsigned long long)(const void*)(ptr)))

// ---------------------------------------------------------------------------
// Pre-pass: convert fp32 inputs to bf16 in workspace (hidden + w_qkv only;
// w_dense conversion is folded into the qkv dispatch's tail blocks).
// ---------------------------------------------------------------------------
__global__ __launch_bounds__(256) void cvt3_kernel(
    const float* __restrict__ a, u16* __restrict__ oa, long na,
    const float* __restrict__ b, u16* __restrict__ ob, long nb,
    const float* __restrict__ c, u16* __restrict__ oc, long nc) {
    const float* in; u16* out; long n;
    if (blockIdx.y == 0)      { in = a; out = oa; n = na; }
    else if (blockIdx.y == 1) { in = b; out = ob; n = nb; }
    else                      { in = c; out = oc; n = nc; }
    const long i = ((long)blockIdx.x * 256 + threadIdx.x) * 8;
    if (i >= n) return;
    cvt8_f32_bf16(in + i, out + i);
}

// ===========================================================================
// 256x256 8-phase GEMM, v3: asm ds_read + template-faithful 2 barriers/phase
// (m201 schedule: {ds_read ; stage-issue ; s_barrier ; lgkmcnt(0)+SB(0) ;
// setprio(1) MFMA setprio(0) ; [vmcnt(4) at p3] ; s_barrier}).
//   BM=BN=256, BK=64, 512 threads = 8 waves (2M x 4N), per-wave 128x64 out.
//   LDS: 2 dbuf x (A 256x64 + B 256x64) bf16 = 128 KiB. 16B-slot XOR swizzle
//   (slot ^= row&7): linear gld_lds dest + inverse-swizzled global source +
//   swizzled read address (rule 21).
//   Staging issue schedule (tile j, phases 0..3):
//     p0: A-half0(j+1) -> buf (j+1)&1
//     p1: A-half1(j+1) -> buf (j+1)&1
//     p2: B-half0(j+2) -> buf  j&1
//     p3: B-half1(j+2) -> buf  j&1, then vmcnt(4): drains A(j+1)+older,
//         leaves B(j+2) 4 loads in flight across the tile boundary.
//   Race analysis: aLds[nb] (= cur of tile j-1) writes issue in p0 of tile j,
//   after the tile-(j-1) end barrier; every wave's lgkmcnt(0) in p3 preceded
//   that barrier, so all j-1 reads completed. bLds[cur] writes issue in p2,
//   two barriers after the tile-top bf burst's lgkmcnt(0) (in p0). B(j+1)
//   left in flight at the j-1/j boundary targets bLds[nb_j], disjoint from
//   the tile-top reads of bLds[cur_j]; it is drained by tile j's p3 vmcnt(4).
// ===========================================================================

#define GEMM8P_PROLOGUE()                                                      \
    const int t    = threadIdx.x;                                              \
    const int w    = t >> 6;                                                   \
    const int lane = t & 63;                                                   \
    const int quad = lane >> 4;                                                \
    const int l16  = lane & 15;                                                \
    const int sw   = lane & 7;                                                 \
    const int qq = nwgg >> 3, rr = nwgg & 7;                                   \
    const int xcd = blockIdx.x & 7, idx = blockIdx.x >> 3;                     \
    const int wgid = (xcd < rr ? xcd * (qq + 1)                                \
                               : rr * (qq + 1) + (xcd - rr) * qq) + idx;       \
    const int m0 = (wgid / nt) * 256;                                          \
    const int n0 = (wgid % nt) * 256;                                          \
    const int wm = (w >> 2) * 128;                                             \
    const int wn = (w & 3) * 64;                                               \
    const int trow = t >> 3;                                                   \
    const int scol = ((t & 7) ^ (trow & 7)) * 8;                               \
    const long Kl = K;                                                         \
    const u16* Asrc = A + (long)(m0 + trow) * Kl + scol;                       \
    auto stageA = [&](int jt, int h, int b) {                                  \
        _Pragma("unroll")                                                      \
        for (int i = 0; i < 2; i++) {                                          \
            const u16* src = Asrc + (long)(h * 128 + i * 64) * Kl + (long)jt * 64; \
            u16* dst = &aLds[b][0] + h * 8192 + i * 4096 + t * 8;              \
            gld_lds16(src, dst);                                               \
        }                                                                      \
    };                                                                         \
    auto stageB = [&](int jt, int h, int b) {                                  \
        _Pragma("unroll")                                                      \
        for (int i = 0; i < 2; i++) {                                          \
            int rb = n0 + h * 128 + i * 64 + trow;                             \
            if (rb > N - 1) rb = N - 1;                                        \
            const u16* src = B + (long)rb * Kl + scol + (long)jt * 64;         \
            u16* dst = &bLds[b][0] + h * 8192 + i * 4096 + t * 8;              \
            gld_lds16(src, dst);                                               \
        }                                                                      \
    };                                                                         \
    floatx4 acc[8][4];                                                         \
    const floatx4 zf4 = {0.f, 0.f, 0.f, 0.f};                                  \
    _Pragma("unroll")                                                          \
    for (int i = 0; i < 8; i++)                                                \
        _Pragma("unroll")                                                      \
        for (int j = 0; j < 4; j++) acc[i][j] = zf4;                           \
    /* prologue: K-tile 0 fully + B halves of K-tile 1 */                      \
    stageA(0, 0, 0); stageA(0, 1, 0);                                          \
    stageB(0, 0, 0); stageB(0, 1, 0);                                          \
    stageB(1, 0, 1); stageB(1, 1, 1);                                          \
    asm volatile("s_waitcnt vmcnt(4)" ::: "memory");                           \
    __builtin_amdgcn_s_barrier();

#define GPHASE(P, STAGE_STMT, TAIL_VM)                                         \
    {                                                                          \
        short8 afA[2], afB[2];                                                 \
        DSR(afA[0], Ac + (wm + (2 * (P)) * 16 + l16) * 64 + ((quad) ^ sw) * 8);\
        DSR(afB[0], Ac + (wm + (2 * (P) + 1) * 16 + l16) * 64 + ((quad) ^ sw) * 8); \
        DSR(afA[1], Ac + (wm + (2 * (P)) * 16 + l16) * 64 + ((4 + quad) ^ sw) * 8); \
        DSR(afB[1], Ac + (wm + (2 * (P) + 1) * 16 + l16) * 64 + ((4 + quad) ^ sw) * 8); \
        STAGE_STMT;                                                            \
        __builtin_amdgcn_s_barrier();                                          \
        asm volatile("s_waitcnt lgkmcnt(0)" ::: "memory");                     \
        __builtin_amdgcn_sched_barrier(0);                                     \
        __builtin_amdgcn_s_setprio(1);                                         \
        _Pragma("unroll")                                                      \
        for (int ks = 0; ks < 2; ks++) {                                       \
            _Pragma("unroll")                                                  \
            for (int ni = 0; ni < 4; ni++) {                                   \
                acc[2 * (P)][ni] = __builtin_amdgcn_mfma_f32_16x16x32_bf16(    \
                    afA[ks], bf[ni][ks], acc[2 * (P)][ni], 0, 0, 0);           \
                acc[2 * (P) + 1][ni] = __builtin_amdgcn_mfma_f32_16x16x32_bf16(\
                    afB[ks], bf[ni][ks], acc[2 * (P) + 1][ni], 0, 0, 0);       \
            }                                                                  \
        }                                                                      \
        __builtin_amdgcn_s_setprio(0);                                         \
        TAIL_VM;                                                               \
        __builtin_amdgcn_s_barrier();                                          \
    }

#define GEMM8P_KLOOP()                                                         \
    const int JT = K >> 6;                                                     \
    for (int j = 0; j < JT; ++j) {                                             \
        const int cur = j & 1;                                                 \
        const int nb  = cur ^ 1;                                               \
        const int jn1 = (j + 1 < JT) ? j + 1 : JT - 1;                         \
        const int jn2 = (j + 2 < JT) ? j + 2 : JT - 1;                         \
        const u16* Ac = &aLds[cur][0];                                         \
        const u16* Bc = &bLds[cur][0];                                         \
        short8 bf[4][2];                                                       \
        _Pragma("unroll")                                                      \
        for (int ni = 0; ni < 4; ni++)                                         \
            _Pragma("unroll")                                                  \
            for (int ks = 0; ks < 2; ks++)                                     \
                DSR(bf[ni][ks],                                                \
                    Bc + (wn + ni * 16 + l16) * 64 + ((4 * ks + quad) ^ sw) * 8); \
        GPHASE(0, stageA(jn1, 0, nb), );                                       \
        GPHASE(1, stageA(jn1, 1, nb), );                                       \
        GPHASE(2, stageB(jn2, 0, cur), );                                      \
        GPHASE(3, stageB(jn2, 1, cur),                                         \
               asm volatile("s_waitcnt vmcnt(4)" ::: "memory"));               \
    }                                                                          \
    asm volatile("s_waitcnt vmcnt(0)" ::: "memory");

// ---------------------------------------------------------------------------
// QKV projection, 8-phase v3, fused RoPE epilogue. Writes q[n][h][l][64]
// (x0.125 folded), k[n][l][64], V transposed vt[n][d][l].
// Tail blocks (blockIdx.x >= nwgg) convert w_dense fp32->bf16 on the CUs
// idle during the 152-block GEMM (gemm_dense runs 2 dispatches later).
// ---------------------------------------------------------------------------
__global__ __launch_bounds__(512, 2) void gemm_qkv_8p(
    const u16* __restrict__ A, const u16* __restrict__ B,
    u16* __restrict__ qb, u16* __restrict__ kb, u16* __restrict__ vt,
    int M, int N, int K, int nt,
    const float* __restrict__ cvt_src, u16* __restrict__ cvt_dst, long cvt_n) {
    __shared__ __align__(16) u16 aLds[2][256 * 64];
    __shared__ __align__(16) u16 bLds[2][256 * 64];
    const int nwgg = (M >> 8) * nt;
    if ((int)blockIdx.x >= nwgg) {
        const long blockbase = (long)((int)blockIdx.x - nwgg) * 16384;
#pragma unroll
        for (int u = 0; u < 4; u++) {
            const long i = blockbase + (long)u * 4096 + (long)threadIdx.x * 8;
            if (i < cvt_n) cvt8_f32_bf16(cvt_src + i, cvt_dst + i);
        }
        return;
    }
    GEMM8P_PROLOGUE()
    GEMM8P_KLOOP()

    // ---- fused RoPE epilogue (C/D: col=l16, row=quad*4+r) ----
#pragma unroll
    for (int ni = 0; ni < 4; ni++) {
        const int c = n0 + wn + ni * 16 + l16;
        if (c >= N) continue;
        const int hh = c >> 6;
        const int d  = c & 63;
        float inv = 0.f;
        if (hh < 72) inv = expf((float)(2 * (d & 31)) * (-0.14391156831212787f));
#pragma unroll
        for (int mi = 0; mi < 8; mi++) {
#pragma unroll
            for (int r = 0; r < 4; r++) {
                const int row = m0 + wm + mi * 16 + quad * 4 + r;   // token
                const int tn = row >> 10;
                const int tl = row & 1023;
                float val = acc[mi][ni][r];
                if (hh < 72) {
                    float sv, cv;
                    sincosf((float)tl * inv, &sv, &cv);
                    const float pacc = acc[mi][ni ^ 2][r];          // col c^32
                    val = val * cv + ((d < 32) ? -pacc : pacc) * sv;
                }
                if (hh < 71) {
                    qb[((long)((tn * 71 + hh) * 1024 + tl)) * 64 + d] = f2bf(val * 0.125f);
                } else if (hh == 71) {
                    kb[((long)(tn * 1024 + tl)) * 64 + d] = f2bf(val);
                } else {
                    vt[((long)(tn * 64 + d)) * 1024 + tl] = f2bf(val);  // V^T
                }
            }
        }
    }
}

// ---------------------------------------------------------------------------
// Dense projection, 8-phase v3: C_fp32[M,N] = A_bf16[M,K]*B_bf16[N,K]^T.
// ---------------------------------------------------------------------------
__global__ __launch_bounds__(512, 2) void gemm_dense_8p(
    const u16* __restrict__ A, const u16* __restrict__ B,
    float* __restrict__ C, int M, int N, int K, int nt) {
    __shared__ __align__(16) u16 aLds[2][256 * 64];
    __shared__ __align__(16) u16 bLds[2][256 * 64];
    const int nwgg = (M >> 8) * nt;
    GEMM8P_PROLOGUE()
    GEMM8P_KLOOP()

#pragma unroll
    for (int ni = 0; ni < 4; ni++) {
        const int col = n0 + wn + ni * 16 + l16;
        if (col >= N) continue;
#pragma unroll
        for (int mi = 0; mi < 8; mi++) {
#pragma unroll
            for (int r = 0; r < 4; r++) {
                const int row = m0 + wm + mi * 16 + quad * 4 + r;
                C[(long)row * N + col] = acc[mi][ni][r];
            }
        }
    }
}

// ---------------------------------------------------------------------------
// Flash-style MQA causal attention v2 (unchanged this round).
// ---------------------------------------------------------------------------
__global__ __launch_bounds__(256) void attn_kernel2(const u16* __restrict__ qb,
                                                    const u16* __restrict__ kb,
                                                    const u16* __restrict__ vt,
                                                    u16* __restrict__ ao) {
    __shared__ __align__(16) u16 k_lds[2][64 * 72];
    __shared__ __align__(16) u16 v_lds[2][64 * 72];
    __shared__ __align__(16) u16 p_lds[4][16 * 72];
    const int qt2 = blockIdx.x;
    const int h   = blockIdx.y;
    const int n   = blockIdx.z;
    const int t    = threadIdx.x;
    const int w    = t >> 6;
    const int lane = t & 63;
    const int quad = lane >> 4;
    const int l16  = lane & 15;
    const int Q0 = qt2 * 128;

    short8 aq[2][2];
#pragma unroll
    for (int mf = 0; mf < 2; mf++) {
        const u16* qrow = qb +
            ((long)((n * 71 + h) * 1024 + Q0 + 64 * mf + w * 16 + l16)) * 64;
        aq[mf][0] = *(const short8*)(qrow + quad * 8);
        aq[mf][1] = *(const short8*)(qrow + 32 + quad * 8);
    }

    floatx4 o[2][4];
    float lst[2][4];
    const floatx4 zf4 = {0.f, 0.f, 0.f, 0.f};
#pragma unroll
    for (int mf = 0; mf < 2; mf++) {
#pragma unroll
        for (int i = 0; i < 4; i++) { o[mf][i] = zf4; lst[mf][i] = 0.f; }
    }

    const int srow = t >> 2;
    const int scol = (t & 3) * 16;
    const u16* kb_n = kb + (long)n * 1024 * 64;
    const u16* vt_n = vt + (long)n * 64 * 1024;
    u16* pw = p_lds[w];

    const int ktend = 2 * qt2 + 2;

    auto stage = [&](int kt, int b) {
        const u16* krow = kb_n + (long)(kt * 64 + srow) * 64 + scol;
        *(uint4*)(k_lds[b] + srow * 72 + scol)     = *(const uint4*)(krow);
        *(uint4*)(k_lds[b] + srow * 72 + scol + 8) = *(const uint4*)(krow + 8);
        const u16* vrow = vt_n + (long)srow * 1024 + kt * 64 + scol;
        *(uint4*)(v_lds[b] + srow * 72 + scol)     = *(const uint4*)(vrow);
        *(uint4*)(v_lds[b] + srow * 72 + scol + 8) = *(const uint4*)(vrow + 8);
    };

    stage(0, 0);
    for (int kt = 0; kt < ktend; kt++) {
        const int buf = kt & 1;
        __syncthreads();
        if (kt + 1 < ktend) stage(kt + 1, 1 - buf);

#pragma unroll
        for (int mf = 0; mf < 2; mf++) {
            if (mf == 0 && kt == 2 * qt2 + 1) continue;
            floatx4 s[4];
#pragma unroll
            for (int sub = 0; sub < 4; sub++) {
                const short8 b0 = *(const short8*)(k_lds[buf] + (sub * 16 + l16) * 72 + quad * 8);
                const short8 b1 = *(const short8*)(k_lds[buf] + (sub * 16 + l16) * 72 + 32 + quad * 8);
                floatx4 z = zf4;
                z = __builtin_amdgcn_mfma_f32_16x16x32_bf16(aq[mf][0], b0, z, 0, 0, 0);
                z = __builtin_amdgcn_mfma_f32_16x16x32_bf16(aq[mf][1], b1, z, 0, 0, 0);
                s[sub] = z;
            }
            const bool diag = (kt == 2 * qt2 + mf);
            const int rowb = Q0 + 64 * mf + w * 16 + quad * 4;
#pragma unroll
            for (int sub = 0; sub < 4; sub++) {
                const int key = kt * 64 + sub * 16 + l16;
#pragma unroll
                for (int r = 0; r < 4; r++) {
                    float p = __expf(s[sub][r]);
                    if (diag && key > rowb + r) p = 0.f;
                    lst[mf][r] += p;
                    pw[(quad * 4 + r) * 72 + sub * 16 + l16] = f2bf(p);
                }
            }
            const short8 ap0 = *(const short8*)(pw + l16 * 72 + quad * 8);
            const short8 ap1 = *(const short8*)(pw + l16 * 72 + 32 + quad * 8);
#pragma unroll
            for (int dch = 0; dch < 4; dch++) {
                const short8 bv0 = *(const short8*)(v_lds[buf] + (dch * 16 + l16) * 72 + quad * 8);
                const short8 bv1 = *(const short8*)(v_lds[buf] + (dch * 16 + l16) * 72 + 32 + quad * 8);
                o[mf][dch] = __builtin_amdgcn_mfma_f32_16x16x32_bf16(ap0, bv0, o[mf][dch], 0, 0, 0);
                o[mf][dch] = __builtin_amdgcn_mfma_f32_16x16x32_bf16(ap1, bv1, o[mf][dch], 0, 0, 0);
            }
        }
    }

    float lsum[2][4];
#pragma unroll
    for (int mf = 0; mf < 2; mf++) {
#pragma unroll
        for (int r = 0; r < 4; r++) {
            float v = lst[mf][r];
#pragma unroll
            for (int mk = 1; mk < 16; mk <<= 1) v += __shfl_xor(v, mk, 64);
            lsum[mf][r] = v;
        }
    }
#pragma unroll
    for (int mf = 0; mf < 2; mf++) {
#pragma unroll
        for (int dch = 0; dch < 4; dch++) {
#pragma unroll
            for (int r = 0; r < 4; r++) {
                const float val = o[mf][dch][r] / lsum[mf][r];
                const int row = n * 1024 + Q0 + 64 * mf + w * 16 + quad * 4 + r;
                const int col = h * 64 + dch * 16 + l16;
                ao[(long)row * 4544 + col] = f2bf(val);
            }
        }
    }
}

// ---------------------------------------------------------------------------
// Fallback path kernels (fp32 staging) — used only if ws too small.
// ---------------------------------------------------------------------------
__global__ __launch_bounds__(256) void gemm_qkv_f32(const float* __restrict__ A,
                                                    const float* __restrict__ B,
                                                    u16* __restrict__ qb,
                                                    u16* __restrict__ kb,
                                                    u16* __restrict__ vt,
                                                    int M, int N, int K) {
    __shared__ __align__(16) u16 a_lds[128 * 32];
    __shared__ __align__(16) u16 b_lds[128 * 32];
    const int t    = threadIdx.x;
    const int lane = t & 63;
    const int w    = t >> 6;
    const int quad = lane >> 4;
    const int l16  = lane & 15;
    const int m0 = blockIdx.y * 128;
    const int n0 = blockIdx.x * 128;
    const int wm = (w >> 1) * 64;
    const int wn = (w & 1) * 64;
    const int srow = t >> 2;
    const int scol = (t & 3) * 8;
    const float* Ap0 = A + (long)(m0 + srow) * K + scol;
    const float* Ap1 = A + (long)(m0 + 64 + srow) * K + scol;
    int bn0 = n0 + srow;      if (bn0 >= N) bn0 = N - 1;
    int bn1 = n0 + 64 + srow; if (bn1 >= N) bn1 = N - 1;
    const float* Bp0 = B + (long)bn0 * K + scol;
    const float* Bp1 = B + (long)bn1 * K + scol;
    u16* as0 = a_lds + srow * 32 + scol;
    u16* as1 = a_lds + (64 + srow) * 32 + scol;
    u16* bs0 = b_lds + srow * 32 + scol;
    u16* bs1 = b_lds + (64 + srow) * 32 + scol;
    floatx4 acc[4][4];
    const floatx4 zf4 = {0.f, 0.f, 0.f, 0.f};
#pragma unroll
    for (int i = 0; i < 4; i++)
#pragma unroll
        for (int j = 0; j < 4; j++) acc[i][j] = zf4;
    for (int k0 = 0; k0 < K; k0 += 32) {
        cvt8_f32_bf16(Ap0 + k0, as0);
        cvt8_f32_bf16(Ap1 + k0, as1);
        cvt8_f32_bf16(Bp0 + k0, bs0);
        cvt8_f32_bf16(Bp1 + k0, bs1);
        __syncthreads();
        short8 af[4], bfr[4];
#pragma unroll
        for (int i = 0; i < 4; i++)
            af[i] = *(const short8*)(a_lds + (wm + i * 16 + l16) * 32 + quad * 8);
#pragma unroll
        for (int j = 0; j < 4; j++)
            bfr[j] = *(const short8*)(b_lds + (wn + j * 16 + l16) * 32 + quad * 8);
#pragma unroll
        for (int i = 0; i < 4; i++)
#pragma unroll
            for (int j = 0; j < 4; j++)
                acc[i][j] = __builtin_amdgcn_mfma_f32_16x16x32_bf16(af[i], bfr[j], acc[i][j], 0, 0, 0);
        __syncthreads();
    }
#pragma unroll
    for (int j = 0; j < 4; j++) {
        const int c = n0 + wn + j * 16 + l16;
        if (c >= N) continue;
        const int hh = c >> 6;
        const int d  = c & 63;
        float inv = 0.f;
        if (hh < 72) inv = expf((float)(2 * (d & 31)) * (-0.14391156831212787f));
#pragma unroll
        for (int i = 0; i < 4; i++) {
#pragma unroll
            for (int r = 0; r < 4; r++) {
                const int row = m0 + wm + i * 16 + quad * 4 + r;
                const int tn = row >> 10;
                const int tl = row & 1023;
                float val = acc[i][j][r];
                if (hh < 72) {
                    float sv, cv;
                    sincosf((float)tl * inv, &sv, &cv);
                    const float pacc = acc[i][j ^ 2][r];
                    val = val * cv + ((d < 32) ? -pacc : pacc) * sv;
                }
                if (hh < 71) {
                    qb[((long)((tn * 71 + hh) * 1024 + tl)) * 64 + d] = f2bf(val * 0.125f);
                } else if (hh == 71) {
                    kb[((long)(tn * 1024 + tl)) * 64 + d] = f2bf(val);
                } else {
                    vt[((long)(tn * 64 + d)) * 1024 + tl] = f2bf(val);
                }
            }
        }
    }
}

__global__ __launch_bounds__(256) void gemm_dense_f32(const u16* __restrict__ A,
                                                      const float* __restrict__ B,
                                                      float* __restrict__ C,
                                                      int M, int N, int K) {
    __shared__ __align__(16) u16 a_lds[128 * 32];
    __shared__ __align__(16) u16 b_lds[128 * 32];
    const int t    = threadIdx.x;
    const int lane = t & 63;
    const int w    = t >> 6;
    const int quad = lane >> 4;
    const int l16  = lane & 15;
    const int m0 = blockIdx.y * 128;
    const int n0 = blockIdx.x * 128;
    const int wm = (w >> 1) * 64;
    const int wn = (w & 1) * 64;
    const int srow = t >> 2;
    const int scol = (t & 3) * 8;
    const u16* Ap0 = A + (long)(m0 + srow) * K + scol;
    const u16* Ap1 = A + (long)(m0 + 64 + srow) * K + scol;
    int bn0 = n0 + srow;      if (bn0 >= N) bn0 = N - 1;
    int bn1 = n0 + 64 + srow; if (bn1 >= N) bn1 = N - 1;
    const float* Bp0 = B + (long)bn0 * K + scol;
    const float* Bp1 = B + (long)bn1 * K + scol;
    u16* as0 = a_lds + srow * 32 + scol;
    u16* as1 = a_lds + (64 + srow) * 32 + scol;
    u16* bs0 = b_lds + srow * 32 + scol;
    u16* bs1 = b_lds + (64 + srow) * 32 + scol;
    floatx4 acc[4][4];
    const floatx4 zf4 = {0.f, 0.f, 0.f, 0.f};
#pragma unroll
    for (int i = 0; i < 4; i++)
#pragma unroll
        for (int j = 0; j < 4; j++) acc[i][j] = zf4;
    for (int k0 = 0; k0 < K; k0 += 32) {
        *(uint4*)as0 = *(const uint4*)(Ap0 + k0);
        *(uint4*)as1 = *(const uint4*)(Ap1 + k0);
        cvt8_f32_bf16(Bp0 + k0, bs0);
        cvt8_f32_bf16(Bp1 + k0, bs1);
        __syncthreads();
        short8 af[4], bfr[4];
#pragma unroll
        for (int i = 0; i < 4; i++)
            af[i] = *(const short8*)(a_lds + (wm + i * 16 + l16) * 32 + quad * 8);
#pragma unroll
        for (int j = 0; j < 4; j++)
            bfr[j] = *(const short8*)(b_lds + (wn + j * 16 + l16) * 32 + quad * 8);
#pragma unroll
        for (int i = 0; i < 4; i++)
#pragma unroll
            for (int j = 0; j < 4; j++)
                acc[i][j] = __builtin_amdgcn_mfma_f32_16x16x32_bf16(af[i], bfr[j], acc[i][j], 0, 0, 0);
        __syncthreads();
    }
#pragma unroll
    for (int i = 0; i < 4; i++) {
#pragma unroll
        for (int j = 0; j < 4; j++) {
            const int col = n0 + wn + j * 16 + l16;
            if (col < N) {
#pragma unroll
                for (int r = 0; r < 4; r++) {
                    const int row = m0 + wm + i * 16 + quad * 4 + r;
                    C[(long)row * N + col] = acc[i][j][r];
                }
            }
        }
    }
}

// ---------------------------------------------------------------------------
extern "C" void kernel_launch(void* const* d_in, const int* in_sizes, int n_in,
                              void* d_out, int out_size, void* d_ws, size_t ws_size,
                              hipStream_t stream) {
    (void)in_sizes; (void)n_in; (void)out_size;
    const float* hidden  = (const float*)d_in[0];   // (2,1024,4544) fp32
    const float* w_qkv   = (const float*)d_in[1];   // (4672,4544)  fp32
    const float* w_dense = (const float*)d_in[2];   // (4544,4544)  fp32
    float* out = (float*)d_out;                     // (2,1024,4544) fp32

    const long N_HID = (long)2048 * 4544;
    const long N_QKV = (long)4672 * 4544;
    const long N_DEN = (long)4544 * 4544;
    const long N_Q   = (long)2 * 71 * 1024 * 64;
    const long N_KV  = (long)2 * 1024 * 64;
    const long N_AO  = (long)2048 * 4544;

    const size_t needA = (size_t)(N_HID + N_QKV + N_DEN + N_Q + 2 * N_KV + N_AO) * 2;

    if (ws_size >= needA) {
        // ---- Path A: bf16 pre-convert + 8-phase 256^2 GEMMs ----
        u16* hid_bf  = (u16*)d_ws;
        u16* wqkv_bf = hid_bf + N_HID;
        u16* wden_bf = wqkv_bf + N_QKV;
        u16* qbuf    = wden_bf + N_DEN;
        u16* kbuf    = qbuf + N_Q;
        u16* vtbuf   = kbuf + N_KV;    // V^T: [n][64][1024]
        u16* aout    = vtbuf + N_KV;

        // hidden + w_qkv only (w_dense cvt folded into qkv dispatch tail)
        cvt3_kernel<<<dim3(10366, 2), 256, 0, stream>>>(
            hidden, hid_bf, N_HID, w_qkv, wqkv_bf, N_QKV, w_dense, wden_bf, N_DEN);
        // M=2048 (8 tiles), N=4672 (19 tiles), K=4544 (71 K-tiles)
        // + 1261 tail blocks converting w_dense (20,647,936 elems / 16384)
        gemm_qkv_8p<<<dim3(8 * 19 + 1261), 512, 0, stream>>>(
            hid_bf, wqkv_bf, qbuf, kbuf, vtbuf,
            2048, 4672, 4544, 19,
            w_dense, wden_bf, N_DEN);
        attn_kernel2<<<dim3(8, 71, 2), 256, 0, stream>>>(qbuf, kbuf, vtbuf, aout);
        // M=2048 (8 tiles), N=4544 (18 tiles)
        gemm_dense_8p<<<dim3(8 * 18), 512, 0, stream>>>(aout, wden_bf, out,
                                                        2048, 4544, 4544, 18);
    } else {
        // ---- Path B: fallback (fp32 staging conversion) ----
        u16* qbuf  = (u16*)d_ws;
        u16* kbuf  = qbuf + N_Q;
        u16* vtbuf = kbuf + N_KV;
        u16* aout  = vtbuf + N_KV;
        gemm_qkv_f32<<<dim3(37, 16), 256, 0, stream>>>(hidden, w_qkv,
                                                       qbuf, kbuf, vtbuf,
                                                       2048, 4672, 4544);
        attn_kernel2<<<dim3(8, 71, 2), 256, 0, stream>>>(qbuf, kbuf, vtbuf, aout);
        gemm_dense_f32<<<dim3(36, 16), 256, 0, stream>>>(aout, w_dense, out,
                                                         2048, 4544, 4544);
    }
}

// Round 5
// 527.772 us; speedup vs baseline: 1.1803x; 1.0179x over previous
//
#include <hip/hip_runtime.h>

typedef unsigned short u16;
typedef __attribute__((ext_vector_type(8))) short short8;   // 8 bf16 = 4 VGPRs (MFMA A/B frag)
typedef __attribute__((ext_vector_type(4))) float floatx4;  // MFMA C/D frag

__device__ __forceinline__ u16 f2bf(float f) {
    union { float f; unsigned int u; } v;
    v.f = f;
    unsigned int u = v.u;
    return (u16)((u + 0x7FFFu + ((u >> 16) & 1u)) >> 16);  // RNE
}

__device__ __forceinline__ void cvt8_f32_bf16(const float* __restrict__ p, u16* dst) {
    const float4 x = *(const float4*)p;
    const float4 y = *(const float4*)(p + 4);
    short8 s;
    s[0] = (short)f2bf(x.x); s[1] = (short)f2bf(x.y);
    s[2] = (short)f2bf(x.z); s[3] = (short)f2bf(x.w);
    s[4] = (short)f2bf(y.x); s[5] = (short)f2bf(y.y);
    s[6] = (short)f2bf(y.z); s[7] = (short)f2bf(y.w);
    *(short8*)dst = s;
}

// async global->LDS DMA, 16B per lane. LDS dest wave-uniform base + lane*16.
__device__ __forceinline__ void gld_lds16(const u16* g, u16* l) {
    __builtin_amdgcn_global_load_lds(
        (const __attribute__((address_space(1))) void*)g,
        (__attribute__((address_space(3))) void*)l,
        16, 0, 0);
}

// Inline-asm ds_read_b128: invisible to SIInsertWaitcnts (no conservative
// vmcnt drains against outstanding LDS-DMA). All waits owned manually:
// counted lgkmcnt + sched_barrier(0) (rule 18), counted vmcnt per K-tile.
#define DSR(dst, ptr)                                                          \
    asm volatile("ds_read_b128 %0, %1"                                         \
                 : "=v"(dst)                                                   \
                 : "v"((unsigned)(unsigned long long)(const void*)(ptr)))

// ---------------------------------------------------------------------------
// Pre-pass: convert fp32 inputs to bf16 in workspace (hidden + w_qkv only;
// w_dense conversion is folded into the qkv dispatch's tail blocks).
// ---------------------------------------------------------------------------
__global__ __launch_bounds__(256) void cvt3_kernel(
    const float* __restrict__ a, u16* __restrict__ oa, long na,
    const float* __restrict__ b, u16* __restrict__ ob, long nb,
    const float* __restrict__ c, u16* __restrict__ oc, long nc) {
    const float* in; u16* out; long n;
    if (blockIdx.y == 0)      { in = a; out = oa; n = na; }
    else if (blockIdx.y == 1) { in = b; out = ob; n = nb; }
    else                      { in = c; out = oc; n = nc; }
    const long i = ((long)blockIdx.x * 256 + threadIdx.x) * 8;
    if (i >= n) return;
    cvt8_f32_bf16(in + i, out + i);
}

// ===========================================================================
// 256x256 GEMM, v4: counted-lgkm software pipeline, 2 barriers per K-tile.
//   BM=BN=256, BK=64, 512 threads = 8 waves (2M x 4N), per-wave 128x64 out.
//   LDS: 2 dbuf x (A 256x64 + B 256x64) bf16 = 128 KiB. 16B-slot XOR swizzle
//   (slot ^= row&7): linear gld_lds dest + inverse-swizzled global source +
//   swizzled read address (rule 21).
//
//   Per K-tile j (phases p0..p3 read the SAME buffer -> no intra-tile
//   barriers needed for the A path; counted lgkm waits overlap next-phase
//   ds_reads with current-phase MFMA in the SAME wave):
//     issue bf[8] + a0[4]            (12 LGKM outstanding)
//     stageA(j+1,h0)->aLds[nb]
//     lgkmcnt(0)                      // bf + a0 ready
//     issue a1[4]; MFMA p0            // a1 drains under MFMA
//     stageA(j+1,h1); issue a2[4]; lgkmcnt(4)  // a1 ready (in-order DS)
//     MFMA p1
//     s_barrier  (MID: every wave passed lgkmcnt(0) -> all B reads complete
//                 -> safe to overwrite bLds[cur] with B(j+2) DMA)
//     stageB(j+2,h0)->bLds[cur]; issue a3[4]; lgkmcnt(4)  // a2 ready
//     MFMA p2
//     stageB(j+2,h1); lgkmcnt(0)      // a3 ready
//     MFMA p3
//     vmcnt(4)   // drains A(j+1)+B(j+1), leaves B(j+2) 4 loads in flight
//     s_barrier  (tile end)
//   In-flight ledger across tile boundary: exactly stageB(j+2) (4 loads) --
//   same invariant as the R3 kernel that passed. aLds[nb] written only by
//   stageA(j+1), read first at tile j+1 top (after vmcnt(4)+barrier). OK.
// ===========================================================================

#define GEMM8P_PROLOGUE()                                                      \
    const int t    = threadIdx.x;                                              \
    const int w    = t >> 6;                                                   \
    const int lane = t & 63;                                                   \
    const int quad = lane >> 4;                                                \
    const int l16  = lane & 15;                                                \
    const int sw   = lane & 7;                                                 \
    const int qq = nwgg >> 3, rr = nwgg & 7;                                   \
    const int xcd = blockIdx.x & 7, idx = blockIdx.x >> 3;                     \
    const int wgid = (xcd < rr ? xcd * (qq + 1)                                \
                               : rr * (qq + 1) + (xcd - rr) * qq) + idx;       \
    const int m0 = (wgid / nt) * 256;                                          \
    const int n0 = (wgid % nt) * 256;                                          \
    const int wm = (w >> 2) * 128;                                             \
    const int wn = (w & 3) * 64;                                               \
    const int trow = t >> 3;                                                   \
    const int scol = ((t & 7) ^ (trow & 7)) * 8;                               \
    const long Kl = K;                                                         \
    const u16* Asrc = A + (long)(m0 + trow) * Kl + scol;                       \
    auto stageA = [&](int jt, int h, int b) {                                  \
        _Pragma("unroll")                                                      \
        for (int i = 0; i < 2; i++) {                                          \
            const u16* src = Asrc + (long)(h * 128 + i * 64) * Kl + (long)jt * 64; \
            u16* dst = &aLds[b][0] + h * 8192 + i * 4096 + t * 8;              \
            gld_lds16(src, dst);                                               \
        }                                                                      \
    };                                                                         \
    auto stageB = [&](int jt, int h, int b) {                                  \
        _Pragma("unroll")                                                      \
        for (int i = 0; i < 2; i++) {                                          \
            int rb = n0 + h * 128 + i * 64 + trow;                             \
            if (rb > N - 1) rb = N - 1;                                        \
            const u16* src = B + (long)rb * Kl + scol + (long)jt * 64;         \
            u16* dst = &bLds[b][0] + h * 8192 + i * 4096 + t * 8;              \
            gld_lds16(src, dst);                                               \
        }                                                                      \
    };                                                                         \
    floatx4 acc[8][4];                                                         \
    const floatx4 zf4 = {0.f, 0.f, 0.f, 0.f};                                  \
    _Pragma("unroll")                                                          \
    for (int i = 0; i < 8; i++)                                                \
        _Pragma("unroll")                                                      \
        for (int j = 0; j < 4; j++) acc[i][j] = zf4;                           \
    /* prologue: K-tile 0 fully + B halves of K-tile 1 */                      \
    stageA(0, 0, 0); stageA(0, 1, 0);                                          \
    stageB(0, 0, 0); stageB(0, 1, 0);                                          \
    stageB(1, 0, 1); stageB(1, 1, 1);                                          \
    asm volatile("s_waitcnt vmcnt(4)" ::: "memory");                           \
    __builtin_amdgcn_s_barrier();

// issue the 4 A-frag ds_reads of phase P (rows 2P*16 and (2P+1)*16)
#define ARD(P, rA, rB)                                                         \
    DSR(rA[0], Ac + (wm + (2 * (P)) * 16 + l16) * 64 + ((quad) ^ sw) * 8);     \
    DSR(rB[0], Ac + (wm + (2 * (P) + 1) * 16 + l16) * 64 + ((quad) ^ sw) * 8); \
    DSR(rA[1], Ac + (wm + (2 * (P)) * 16 + l16) * 64 + ((4 + quad) ^ sw) * 8); \
    DSR(rB[1], Ac + (wm + (2 * (P) + 1) * 16 + l16) * 64 + ((4 + quad) ^ sw) * 8);

// MFMA cluster of phase P (fenced by sched_barrier so it cannot cross waits)
#define AMM(P, rA, rB)                                                         \
    __builtin_amdgcn_sched_barrier(0);                                         \
    __builtin_amdgcn_s_setprio(1);                                             \
    _Pragma("unroll")                                                          \
    for (int ks = 0; ks < 2; ks++) {                                           \
        _Pragma("unroll")                                                      \
        for (int ni = 0; ni < 4; ni++) {                                       \
            acc[2 * (P)][ni] = __builtin_amdgcn_mfma_f32_16x16x32_bf16(        \
                rA[ks], bf[ni][ks], acc[2 * (P)][ni], 0, 0, 0);                \
            acc[2 * (P) + 1][ni] = __builtin_amdgcn_mfma_f32_16x16x32_bf16(    \
                rB[ks], bf[ni][ks], acc[2 * (P) + 1][ni], 0, 0, 0);            \
        }                                                                      \
    }                                                                          \
    __builtin_amdgcn_s_setprio(0);                                             \
    __builtin_amdgcn_sched_barrier(0);

#define GEMM8P_KLOOP()                                                         \
    const int JT = K >> 6;                                                     \
    for (int j = 0; j < JT; ++j) {                                             \
        const int cur = j & 1;                                                 \
        const int nb  = cur ^ 1;                                               \
        const int jn1 = (j + 1 < JT) ? j + 1 : JT - 1;                         \
        const int jn2 = (j + 2 < JT) ? j + 2 : JT - 1;                         \
        const u16* Ac = &aLds[cur][0];                                         \
        const u16* Bc = &bLds[cur][0];                                         \
        short8 bf[4][2];                                                       \
        short8 aA0[2], aB0[2], aA1[2], aB1[2];                                 \
        short8 aA2[2], aB2[2], aA3[2], aB3[2];                                 \
        _Pragma("unroll")                                                      \
        for (int ni = 0; ni < 4; ni++)                                         \
            _Pragma("unroll")                                                  \
            for (int ks = 0; ks < 2; ks++)                                     \
                DSR(bf[ni][ks],                                                \
                    Bc + (wn + ni * 16 + l16) * 64 + ((4 * ks + quad) ^ sw) * 8); \
        ARD(0, aA0, aB0)                                                       \
        stageA(jn1, 0, nb);                                                    \
        asm volatile("s_waitcnt lgkmcnt(0)" ::: "memory");                     \
        ARD(1, aA1, aB1)                                                       \
        AMM(0, aA0, aB0)                                                       \
        stageA(jn1, 1, nb);                                                    \
        ARD(2, aA2, aB2)                                                       \
        asm volatile("s_waitcnt lgkmcnt(4)" ::: "memory");                     \
        AMM(1, aA1, aB1)                                                       \
        __builtin_amdgcn_s_barrier();  /* mid: B reads complete everywhere */  \
        stageB(jn2, 0, cur);                                                   \
        ARD(3, aA3, aB3)                                                       \
        asm volatile("s_waitcnt lgkmcnt(4)" ::: "memory");                     \
        AMM(2, aA2, aB2)                                                       \
        stageB(jn2, 1, cur);                                                   \
        asm volatile("s_waitcnt lgkmcnt(0)" ::: "memory");                     \
        AMM(3, aA3, aB3)                                                       \
        asm volatile("s_waitcnt vmcnt(4)" ::: "memory");                       \
        __builtin_amdgcn_s_barrier();  /* tile end */                          \
    }                                                                          \
    asm volatile("s_waitcnt vmcnt(0)" ::: "memory");

// ---------------------------------------------------------------------------
// QKV projection, pipelined v4, fused RoPE epilogue. Writes q[n][h][l][64]
// (x0.125 folded), k[n][l][64], V transposed vt[n][d][l].
// Tail blocks (blockIdx.x >= nwgg) convert w_dense fp32->bf16 on the CUs
// idle during the 152-block GEMM (gemm_dense runs 2 dispatches later).
// ---------------------------------------------------------------------------
__global__ __launch_bounds__(512, 2) void gemm_qkv_8p(
    const u16* __restrict__ A, const u16* __restrict__ B,
    u16* __restrict__ qb, u16* __restrict__ kb, u16* __restrict__ vt,
    int M, int N, int K, int nt,
    const float* __restrict__ cvt_src, u16* __restrict__ cvt_dst, long cvt_n) {
    __shared__ __align__(16) u16 aLds[2][256 * 64];
    __shared__ __align__(16) u16 bLds[2][256 * 64];
    const int nwgg = (M >> 8) * nt;
    if ((int)blockIdx.x >= nwgg) {
        const long blockbase = (long)((int)blockIdx.x - nwgg) * 16384;
#pragma unroll
        for (int u = 0; u < 4; u++) {
            const long i = blockbase + (long)u * 4096 + (long)threadIdx.x * 8;
            if (i < cvt_n) cvt8_f32_bf16(cvt_src + i, cvt_dst + i);
        }
        return;
    }
    GEMM8P_PROLOGUE()
    GEMM8P_KLOOP()

    // ---- fused RoPE epilogue (C/D: col=l16, row=quad*4+r) ----
#pragma unroll
    for (int ni = 0; ni < 4; ni++) {
        const int c = n0 + wn + ni * 16 + l16;
        if (c >= N) continue;
        const int hh = c >> 6;
        const int d  = c & 63;
        float inv = 0.f;
        if (hh < 72) inv = expf((float)(2 * (d & 31)) * (-0.14391156831212787f));
#pragma unroll
        for (int mi = 0; mi < 8; mi++) {
#pragma unroll
            for (int r = 0; r < 4; r++) {
                const int row = m0 + wm + mi * 16 + quad * 4 + r;   // token
                const int tn = row >> 10;
                const int tl = row & 1023;
                float val = acc[mi][ni][r];
                if (hh < 72) {
                    float sv, cv;
                    sincosf((float)tl * inv, &sv, &cv);
                    const float pacc = acc[mi][ni ^ 2][r];          // col c^32
                    val = val * cv + ((d < 32) ? -pacc : pacc) * sv;
                }
                if (hh < 71) {
                    qb[((long)((tn * 71 + hh) * 1024 + tl)) * 64 + d] = f2bf(val * 0.125f);
                } else if (hh == 71) {
                    kb[((long)(tn * 1024 + tl)) * 64 + d] = f2bf(val);
                } else {
                    vt[((long)(tn * 64 + d)) * 1024 + tl] = f2bf(val);  // V^T
                }
            }
        }
    }
}

// ---------------------------------------------------------------------------
// Dense projection, pipelined v4: C_fp32[M,N] = A_bf16[M,K]*B_bf16[N,K]^T.
// ---------------------------------------------------------------------------
__global__ __launch_bounds__(512, 2) void gemm_dense_8p(
    const u16* __restrict__ A, const u16* __restrict__ B,
    float* __restrict__ C, int M, int N, int K, int nt) {
    __shared__ __align__(16) u16 aLds[2][256 * 64];
    __shared__ __align__(16) u16 bLds[2][256 * 64];
    const int nwgg = (M >> 8) * nt;
    GEMM8P_PROLOGUE()
    GEMM8P_KLOOP()

#pragma unroll
    for (int ni = 0; ni < 4; ni++) {
        const int col = n0 + wn + ni * 16 + l16;
        if (col >= N) continue;
#pragma unroll
        for (int mi = 0; mi < 8; mi++) {
#pragma unroll
            for (int r = 0; r < 4; r++) {
                const int row = m0 + wm + mi * 16 + quad * 4 + r;
                C[(long)row * N + col] = acc[mi][ni][r];
            }
        }
    }
}

// ---------------------------------------------------------------------------
// Flash-style MQA causal attention v2 (unchanged this round).
// ---------------------------------------------------------------------------
__global__ __launch_bounds__(256) void attn_kernel2(const u16* __restrict__ qb,
                                                    const u16* __restrict__ kb,
                                                    const u16* __restrict__ vt,
                                                    u16* __restrict__ ao) {
    __shared__ __align__(16) u16 k_lds[2][64 * 72];
    __shared__ __align__(16) u16 v_lds[2][64 * 72];
    __shared__ __align__(16) u16 p_lds[4][16 * 72];
    const int qt2 = blockIdx.x;
    const int h   = blockIdx.y;
    const int n   = blockIdx.z;
    const int t    = threadIdx.x;
    const int w    = t >> 6;
    const int lane = t & 63;
    const int quad = lane >> 4;
    const int l16  = lane & 15;
    const int Q0 = qt2 * 128;

    short8 aq[2][2];
#pragma unroll
    for (int mf = 0; mf < 2; mf++) {
        const u16* qrow = qb +
            ((long)((n * 71 + h) * 1024 + Q0 + 64 * mf + w * 16 + l16)) * 64;
        aq[mf][0] = *(const short8*)(qrow + quad * 8);
        aq[mf][1] = *(const short8*)(qrow + 32 + quad * 8);
    }

    floatx4 o[2][4];
    float lst[2][4];
    const floatx4 zf4 = {0.f, 0.f, 0.f, 0.f};
#pragma unroll
    for (int mf = 0; mf < 2; mf++) {
#pragma unroll
        for (int i = 0; i < 4; i++) { o[mf][i] = zf4; lst[mf][i] = 0.f; }
    }

    const int srow = t >> 2;
    const int scol = (t & 3) * 16;
    const u16* kb_n = kb + (long)n * 1024 * 64;
    const u16* vt_n = vt + (long)n * 64 * 1024;
    u16* pw = p_lds[w];

    const int ktend = 2 * qt2 + 2;

    auto stage = [&](int kt, int b) {
        const u16* krow = kb_n + (long)(kt * 64 + srow) * 64 + scol;
        *(uint4*)(k_lds[b] + srow * 72 + scol)     = *(const uint4*)(krow);
        *(uint4*)(k_lds[b] + srow * 72 + scol + 8) = *(const uint4*)(krow + 8);
        const u16* vrow = vt_n + (long)srow * 1024 + kt * 64 + scol;
        *(uint4*)(v_lds[b] + srow * 72 + scol)     = *(const uint4*)(vrow);
        *(uint4*)(v_lds[b] + srow * 72 + scol + 8) = *(const uint4*)(vrow + 8);
    };

    stage(0, 0);
    for (int kt = 0; kt < ktend; kt++) {
        const int buf = kt & 1;
        __syncthreads();
        if (kt + 1 < ktend) stage(kt + 1, 1 - buf);

#pragma unroll
        for (int mf = 0; mf < 2; mf++) {
            if (mf == 0 && kt == 2 * qt2 + 1) continue;
            floatx4 s[4];
#pragma unroll
            for (int sub = 0; sub < 4; sub++) {
                const short8 b0 = *(const short8*)(k_lds[buf] + (sub * 16 + l16) * 72 + quad * 8);
                const short8 b1 = *(const short8*)(k_lds[buf] + (sub * 16 + l16) * 72 + 32 + quad * 8);
                floatx4 z = zf4;
                z = __builtin_amdgcn_mfma_f32_16x16x32_bf16(aq[mf][0], b0, z, 0, 0, 0);
                z = __builtin_amdgcn_mfma_f32_16x16x32_bf16(aq[mf][1], b1, z, 0, 0, 0);
                s[sub] = z;
            }
            const bool diag = (kt == 2 * qt2 + mf);
            const int rowb = Q0 + 64 * mf + w * 16 + quad * 4;
#pragma unroll
            for (int sub = 0; sub < 4; sub++) {
                const int key = kt * 64 + sub * 16 + l16;
#pragma unroll
                for (int r = 0; r < 4; r++) {
                    float p = __expf(s[sub][r]);
                    if (diag && key > rowb + r) p = 0.f;
                    lst[mf][r] += p;
                    pw[(quad * 4 + r) * 72 + sub * 16 + l16] = f2bf(p);
                }
            }
            const short8 ap0 = *(const short8*)(pw + l16 * 72 + quad * 8);
            const short8 ap1 = *(const short8*)(pw + l16 * 72 + 32 + quad * 8);
#pragma unroll
            for (int dch = 0; dch < 4; dch++) {
                const short8 bv0 = *(const short8*)(v_lds[buf] + (dch * 16 + l16) * 72 + quad * 8);
                const short8 bv1 = *(const short8*)(v_lds[buf] + (dch * 16 + l16) * 72 + 32 + quad * 8);
                o[mf][dch] = __builtin_amdgcn_mfma_f32_16x16x32_bf16(ap0, bv0, o[mf][dch], 0, 0, 0);
                o[mf][dch] = __builtin_amdgcn_mfma_f32_16x16x32_bf16(ap1, bv1, o[mf][dch], 0, 0, 0);
            }
        }
    }

    float lsum[2][4];
#pragma unroll
    for (int mf = 0; mf < 2; mf++) {
#pragma unroll
        for (int r = 0; r < 4; r++) {
            float v = lst[mf][r];
#pragma unroll
            for (int mk = 1; mk < 16; mk <<= 1) v += __shfl_xor(v, mk, 64);
            lsum[mf][r] = v;
        }
    }
#pragma unroll
    for (int mf = 0; mf < 2; mf++) {
#pragma unroll
        for (int dch = 0; dch < 4; dch++) {
#pragma unroll
            for (int r = 0; r < 4; r++) {
                const float val = o[mf][dch][r] / lsum[mf][r];
                const int row = n * 1024 + Q0 + 64 * mf + w * 16 + quad * 4 + r;
                const int col = h * 64 + dch * 16 + l16;
                ao[(long)row * 4544 + col] = f2bf(val);
            }
        }
    }
}

// ---------------------------------------------------------------------------
// Fallback path kernels (fp32 staging) — used only if ws too small.
// ---------------------------------------------------------------------------
__global__ __launch_bounds__(256) void gemm_qkv_f32(const float* __restrict__ A,
                                                    const float* __restrict__ B,
                                                    u16* __restrict__ qb,
                                                    u16* __restrict__ kb,
                                                    u16* __restrict__ vt,
                                                    int M, int N, int K) {
    __shared__ __align__(16) u16 a_lds[128 * 32];
    __shared__ __align__(16) u16 b_lds[128 * 32];
    const int t    = threadIdx.x;
    const int lane = t & 63;
    const int w    = t >> 6;
    const int quad = lane >> 4;
    const int l16  = lane & 15;
    const int m0 = blockIdx.y * 128;
    const int n0 = blockIdx.x * 128;
    const int wm = (w >> 1) * 64;
    const int wn = (w & 1) * 64;
    const int srow = t >> 2;
    const int scol = (t & 3) * 8;
    const float* Ap0 = A + (long)(m0 + srow) * K + scol;
    const float* Ap1 = A + (long)(m0 + 64 + srow) * K + scol;
    int bn0 = n0 + srow;      if (bn0 >= N) bn0 = N - 1;
    int bn1 = n0 + 64 + srow; if (bn1 >= N) bn1 = N - 1;
    const float* Bp0 = B + (long)bn0 * K + scol;
    const float* Bp1 = B + (long)bn1 * K + scol;
    u16* as0 = a_lds + srow * 32 + scol;
    u16* as1 = a_lds + (64 + srow) * 32 + scol;
    u16* bs0 = b_lds + srow * 32 + scol;
    u16* bs1 = b_lds + (64 + srow) * 32 + scol;
    floatx4 acc[4][4];
    const floatx4 zf4 = {0.f, 0.f, 0.f, 0.f};
#pragma unroll
    for (int i = 0; i < 4; i++)
#pragma unroll
        for (int j = 0; j < 4; j++) acc[i][j] = zf4;
    for (int k0 = 0; k0 < K; k0 += 32) {
        cvt8_f32_bf16(Ap0 + k0, as0);
        cvt8_f32_bf16(Ap1 + k0, as1);
        cvt8_f32_bf16(Bp0 + k0, bs0);
        cvt8_f32_bf16(Bp1 + k0, bs1);
        __syncthreads();
        short8 af[4], bfr[4];
#pragma unroll
        for (int i = 0; i < 4; i++)
            af[i] = *(const short8*)(a_lds + (wm + i * 16 + l16) * 32 + quad * 8);
#pragma unroll
        for (int j = 0; j < 4; j++)
            bfr[j] = *(const short8*)(b_lds + (wn + j * 16 + l16) * 32 + quad * 8);
#pragma unroll
        for (int i = 0; i < 4; i++)
#pragma unroll
            for (int j = 0; j < 4; j++)
                acc[i][j] = __builtin_amdgcn_mfma_f32_16x16x32_bf16(af[i], bfr[j], acc[i][j], 0, 0, 0);
        __syncthreads();
    }
#pragma unroll
    for (int j = 0; j < 4; j++) {
        const int c = n0 + wn + j * 16 + l16;
        if (c >= N) continue;
        const int hh = c >> 6;
        const int d  = c & 63;
        float inv = 0.f;
        if (hh < 72) inv = expf((float)(2 * (d & 31)) * (-0.14391156831212787f));
#pragma unroll
        for (int i = 0; i < 4; i++) {
#pragma unroll
            for (int r = 0; r < 4; r++) {
                const int row = m0 + wm + i * 16 + quad * 4 + r;
                const int tn = row >> 10;
                const int tl = row & 1023;
                float val = acc[i][j][r];
                if (hh < 72) {
                    float sv, cv;
                    sincosf((float)tl * inv, &sv, &cv);
                    const float pacc = acc[i][j ^ 2][r];
                    val = val * cv + ((d < 32) ? -pacc : pacc) * sv;
                }
                if (hh < 71) {
                    qb[((long)((tn * 71 + hh) * 1024 + tl)) * 64 + d] = f2bf(val * 0.125f);
                } else if (hh == 71) {
                    kb[((long)(tn * 1024 + tl)) * 64 + d] = f2bf(val);
                } else {
                    vt[((long)(tn * 64 + d)) * 1024 + tl] = f2bf(val);
                }
            }
        }
    }
}

__global__ __launch_bounds__(256) void gemm_dense_f32(const u16* __restrict__ A,
                                                      const float* __restrict__ B,
                                                      float* __restrict__ C,
                                                      int M, int N, int K) {
    __shared__ __align__(16) u16 a_lds[128 * 32];
    __shared__ __align__(16) u16 b_lds[128 * 32];
    const int t    = threadIdx.x;
    const int lane = t & 63;
    const int w    = t >> 6;
    const int quad = lane >> 4;
    const int l16  = lane & 15;
    const int m0 = blockIdx.y * 128;
    const int n0 = blockIdx.x * 128;
    const int wm = (w >> 1) * 64;
    const int wn = (w & 1) * 64;
    const int srow = t >> 2;
    const int scol = (t & 3) * 8;
    const u16* Ap0 = A + (long)(m0 + srow) * K + scol;
    const u16* Ap1 = A + (long)(m0 + 64 + srow) * K + scol;
    int bn0 = n0 + srow;      if (bn0 >= N) bn0 = N - 1;
    int bn1 = n0 + 64 + srow; if (bn1 >= N) bn1 = N - 1;
    const float* Bp0 = B + (long)bn0 * K + scol;
    const float* Bp1 = B + (long)bn1 * K + scol;
    u16* as0 = a_lds + srow * 32 + scol;
    u16* as1 = a_lds + (64 + srow) * 32 + scol;
    u16* bs0 = b_lds + srow * 32 + scol;
    u16* bs1 = b_lds + (64 + srow) * 32 + scol;
    floatx4 acc[4][4];
    const floatx4 zf4 = {0.f, 0.f, 0.f, 0.f};
#pragma unroll
    for (int i = 0; i < 4; i++)
#pragma unroll
        for (int j = 0; j < 4; j++) acc[i][j] = zf4;
    for (int k0 = 0; k0 < K; k0 += 32) {
        *(uint4*)as0 = *(const uint4*)(Ap0 + k0);
        *(uint4*)as1 = *(const uint4*)(Ap1 + k0);
        cvt8_f32_bf16(Bp0 + k0, bs0);
        cvt8_f32_bf16(Bp1 + k0, bs1);
        __syncthreads();
        short8 af[4], bfr[4];
#pragma unroll
        for (int i = 0; i < 4; i++)
            af[i] = *(const short8*)(a_lds + (wm + i * 16 + l16) * 32 + quad * 8);
#pragma unroll
        for (int j = 0; j < 4; j++)
            bfr[j] = *(const short8*)(b_lds + (wn + j * 16 + l16) * 32 + quad * 8);
#pragma unroll
        for (int i = 0; i < 4; i++)
#pragma unroll
            for (int j = 0; j < 4; j++)
                acc[i][j] = __builtin_amdgcn_mfma_f32_16x16x32_bf16(af[i], bfr[j], acc[i][j], 0, 0, 0);
        __syncthreads();
    }
#pragma unroll
    for (int i = 0; i < 4; i++) {
#pragma unroll
        for (int j = 0; j < 4; j++) {
            const int col = n0 + wn + j * 16 + l16;
            if (col < N) {
#pragma unroll
                for (int r = 0; r < 4; r++) {
                    const int row = m0 + wm + i * 16 + quad * 4 + r;
                    C[(long)row * N + col] = acc[i][j][r];
                }
            }
        }
    }
}

// ---------------------------------------------------------------------------
extern "C" void kernel_launch(void* const* d_in, const int* in_sizes, int n_in,
                              void* d_out, int out_size, void* d_ws, size_t ws_size,
                              hipStream_t stream) {
    (void)in_sizes; (void)n_in; (void)out_size;
    const float* hidden  = (const float*)d_in[0];   // (2,1024,4544) fp32
    const float* w_qkv   = (const float*)d_in[1];   // (4672,4544)  fp32
    const float* w_dense = (const float*)d_in[2];   // (4544,4544)  fp32
    float* out = (float*)d_out;                     // (2,1024,4544) fp32

    const long N_HID = (long)2048 * 4544;
    const long N_QKV = (long)4672 * 4544;
    const long N_DEN = (long)4544 * 4544;
    const long N_Q   = (long)2 * 71 * 1024 * 64;
    const long N_KV  = (long)2 * 1024 * 64;
    const long N_AO  = (long)2048 * 4544;

    const size_t needA = (size_t)(N_HID + N_QKV + N_DEN + N_Q + 2 * N_KV + N_AO) * 2;

    if (ws_size >= needA) {
        // ---- Path A: bf16 pre-convert + pipelined 256^2 GEMMs ----
        u16* hid_bf  = (u16*)d_ws;
        u16* wqkv_bf = hid_bf + N_HID;
        u16* wden_bf = wqkv_bf + N_QKV;
        u16* qbuf    = wden_bf + N_DEN;
        u16* kbuf    = qbuf + N_Q;
        u16* vtbuf   = kbuf + N_KV;    // V^T: [n][64][1024]
        u16* aout    = vtbuf + N_KV;

        // hidden + w_qkv only (w_dense cvt folded into qkv dispatch tail)
        cvt3_kernel<<<dim3(10366, 2), 256, 0, stream>>>(
            hidden, hid_bf, N_HID, w_qkv, wqkv_bf, N_QKV, w_dense, wden_bf, N_DEN);
        // M=2048 (8 tiles), N=4672 (19 tiles), K=4544 (71 K-tiles)
        // + 1261 tail blocks converting w_dense (20,647,936 elems / 16384)
        gemm_qkv_8p<<<dim3(8 * 19 + 1261), 512, 0, stream>>>(
            hid_bf, wqkv_bf, qbuf, kbuf, vtbuf,
            2048, 4672, 4544, 19,
            w_dense, wden_bf, N_DEN);
        attn_kernel2<<<dim3(8, 71, 2), 256, 0, stream>>>(qbuf, kbuf, vtbuf, aout);
        // M=2048 (8 tiles), N=4544 (18 tiles)
        gemm_dense_8p<<<dim3(8 * 18), 512, 0, stream>>>(aout, wden_bf, out,
                                                        2048, 4544, 4544, 18);
    } else {
        // ---- Path B: fallback (fp32 staging conversion) ----
        u16* qbuf  = (u16*)d_ws;
        u16* kbuf  = qbuf + N_Q;
        u16* vtbuf = kbuf + N_KV;
        u16* aout  = vtbuf + N_KV;
        gemm_qkv_f32<<<dim3(37, 16), 256, 0, stream>>>(hidden, w_qkv,
                                                       qbuf, kbuf, vtbuf,
                                                       2048, 4672, 4544);
        attn_kernel2<<<dim3(8, 71, 2), 256, 0, stream>>>(qbuf, kbuf, vtbuf, aout);
        gemm_dense_f32<<<dim3(36, 16), 256, 0, stream>>>(aout, w_dense, out,
                                                         2048, 4544, 4544);
    }
}

// Round 6
// 502.750 us; speedup vs baseline: 1.2390x; 1.0498x over previous
//
#include <hip/hip_runtime.h>

typedef unsigned short u16;
typedef __attribute__((ext_vector_type(8))) short short8;   // 8 bf16 = 4 VGPRs (MFMA A/B frag)
typedef __attribute__((ext_vector_type(4))) float floatx4;  // MFMA C/D frag

__device__ __forceinline__ u16 f2bf(float f) {
    union { float f; unsigned int u; } v;
    v.f = f;
    unsigned int u = v.u;
    return (u16)((u + 0x7FFFu + ((u >> 16) & 1u)) >> 16);  // RNE
}

__device__ __forceinline__ void cvt8_f32_bf16(const float* __restrict__ p, u16* dst) {
    const float4 x = *(const float4*)p;
    const float4 y = *(const float4*)(p + 4);
    short8 s;
    s[0] = (short)f2bf(x.x); s[1] = (short)f2bf(x.y);
    s[2] = (short)f2bf(x.z); s[3] = (short)f2bf(x.w);
    s[4] = (short)f2bf(y.x); s[5] = (short)f2bf(y.y);
    s[6] = (short)f2bf(y.z); s[7] = (short)f2bf(y.w);
    *(short8*)dst = s;
}

// async global->LDS DMA, 16B per lane. LDS dest wave-uniform base + lane*16.
__device__ __forceinline__ void gld_lds16(const u16* g, u16* l) {
    __builtin_amdgcn_global_load_lds(
        (const __attribute__((address_space(1))) void*)g,
        (__attribute__((address_space(3))) void*)l,
        16, 0, 0);
}

// Inline-asm ds_read_b128: invisible to SIInsertWaitcnts (no conservative
// vmcnt drains against outstanding LDS-DMA). All waits owned manually:
// counted lgkmcnt + sched_barrier(0) (rule 18), counted vmcnt per K-tile.
#define DSR(dst, ptr)                                                          \
    asm volatile("ds_read_b128 %0, %1"                                         \
                 : "=v"(dst)                                                   \
                 : "v"((unsigned)(unsigned long long)(const void*)(ptr)))

// ---------------------------------------------------------------------------
// Pre-pass: convert fp32 inputs to bf16 in workspace (hidden + w_qkv only;
// w_dense conversion is folded into the qkv dispatch's tail blocks).
// ---------------------------------------------------------------------------
__global__ __launch_bounds__(256) void cvt3_kernel(
    const float* __restrict__ a, u16* __restrict__ oa, long na,
    const float* __restrict__ b, u16* __restrict__ ob, long nb,
    const float* __restrict__ c, u16* __restrict__ oc, long nc) {
    const float* in; u16* out; long n;
    if (blockIdx.y == 0)      { in = a; out = oa; n = na; }
    else if (blockIdx.y == 1) { in = b; out = ob; n = nb; }
    else                      { in = c; out = oc; n = nc; }
    const long i = ((long)blockIdx.x * 256 + threadIdx.x) * 8;
    if (i >= n) return;
    cvt8_f32_bf16(in + i, out + i);
}

// ===========================================================================
// 256x256 GEMM v6: cross-tile cluster rotation — every 4-read DS group is
// covered by an 8-MFMA half-cluster, eliminating the tile-top read burst
// that serialized the DS and MFMA pipes in v4/v5 (measured: DS busy 42%,
// tile = DS-time + MFMA-time ≈ 5456 cyc; target max(DS,MFMA) ≈ 3300).
//
//   BM=BN=256, BK=64, 512 threads = 8 waves (2M x 4N), per-wave 128x64 out.
//   LDS: 2 dbuf x (A 256x64 + B 256x64) bf16 = 128 KiB. 16B-slot XOR swizzle
//   (slot ^= row&7): linear gld_lds dest + inverse-swizzled global source +
//   swizzled read address (rule 21).
//
//   Cluster CH(P,ks) = 8 MFMA: acc[2P..2P+1][*] += aP[ks] x bk{ks}[*].
//   bk0 regs die after CH(3,0); bk1 after CH(3,1); aP after CH(P,1) of next
//   use — so next-tile reads issue into DEAD registers under live clusters:
//
//   loop j:  RD_A2 | stageA(j+1,h0) | lgkm(4)[a1] | CH(1,0) CH(1,1)   (a2 drains)
//            RD_A3 | stageA(j+1,h1) | lgkm(4)[a2] | MID barrier
//            stageB(j+2,h0) | CH(2,0) CH(2,1)                          (a3 drains)
//            stageB(j+2,h1) | lgkm(0)[a3] | CH(3,0)                    (bk0 dies)
//            vmcnt(4) | END barrier
//            g: RD_BF0' RD_A0'   | CH(3,1)                             (covers 8 reads)
//            g: lgkm(0)[bf0',a0'] | RD_BF1' RD_A1' | CH(0,0)'          (covers bf1')
//            g: lgkm(4)[bf1']     | CH(0,1)'                           (a1' drains)
//
//   Ledgers (per wave): DS entry [a1]4 -> +a2 -> lgkm4 -> +a3 -> lgkm4 ->
//   lgkm0 -> +bf0',a0' -> lgkm0 -> +bf1',a1' -> lgkm4 -> exit [a1']4. ✓
//   VM: entry [B(j+1)]4; +A(j+1)4 +B(j+2)4 = 12; vmcnt(4) leaves B(j+2). ✓
//   MID barrier: all waves consumed bk reads (prev boundary) before any
//   wave's stageB(j+2) overwrites bLds[cur]. END barrier: all waves drained
//   A(j+1)/B(j+1) DMA before boundary reads of aLds[nb]/bLds[nb]. Same
//   invariants as R3/R5 (both passed on HW).
// ===========================================================================

#define GEMM8P_PROLOGUE()                                                      \
    const int t    = threadIdx.x;                                              \
    const int w    = t >> 6;                                                   \
    const int lane = t & 63;                                                   \
    const int quad = lane >> 4;                                                \
    const int l16  = lane & 15;                                                \
    const int sw   = lane & 7;                                                 \
    const int qq = nwgg >> 3, rr = nwgg & 7;                                   \
    const int xcd = blockIdx.x & 7, idx = blockIdx.x >> 3;                     \
    const int wgid = (xcd < rr ? xcd * (qq + 1)                                \
                               : rr * (qq + 1) + (xcd - rr) * qq) + idx;       \
    const int m0 = (wgid / nt) * 256;                                          \
    const int n0 = (wgid % nt) * 256;                                          \
    const int wm = (w >> 2) * 128;                                             \
    const int wn = (w & 3) * 64;                                               \
    const int trow = t >> 3;                                                   \
    const int scol = ((t & 7) ^ (trow & 7)) * 8;                               \
    const long Kl = K;                                                         \
    const u16* Asrc = A + (long)(m0 + trow) * Kl + scol;                       \
    auto stageA = [&](int jt, int h, int b) {                                  \
        _Pragma("unroll")                                                      \
        for (int i = 0; i < 2; i++) {                                          \
            const u16* src = Asrc + (long)(h * 128 + i * 64) * Kl + (long)jt * 64; \
            u16* dst = &aLds[b][0] + h * 8192 + i * 4096 + t * 8;              \
            gld_lds16(src, dst);                                               \
        }                                                                      \
    };                                                                         \
    auto stageB = [&](int jt, int h, int b) {                                  \
        _Pragma("unroll")                                                      \
        for (int i = 0; i < 2; i++) {                                          \
            int rb = n0 + h * 128 + i * 64 + trow;                             \
            if (rb > N - 1) rb = N - 1;                                        \
            const u16* src = B + (long)rb * Kl + scol + (long)jt * 64;         \
            u16* dst = &bLds[b][0] + h * 8192 + i * 4096 + t * 8;              \
            gld_lds16(src, dst);                                               \
        }                                                                      \
    };                                                                         \
    floatx4 acc[8][4];                                                         \
    const floatx4 zf4 = {0.f, 0.f, 0.f, 0.f};                                  \
    _Pragma("unroll")                                                          \
    for (int i = 0; i < 8; i++)                                                \
        _Pragma("unroll")                                                      \
        for (int j = 0; j < 4; j++) acc[i][j] = zf4;                           \
    /* prologue: K-tile 0 fully + B halves of K-tile 1 */                      \
    stageA(0, 0, 0); stageA(0, 1, 0);                                          \
    stageB(0, 0, 0); stageB(0, 1, 0);                                          \
    stageB(1, 0, 1); stageB(1, 1, 1);                                          \
    asm volatile("s_waitcnt vmcnt(4)" ::: "memory");                           \
    __builtin_amdgcn_s_barrier();

// B-fragment reads, ks half 0 / 1 (4 x ds_read_b128 each)
#define RD_BF0(Bp)                                                             \
    DSR(bk0[0], (Bp) + (wn + 0 * 16 + l16) * 64 + ((quad) ^ sw) * 8);          \
    DSR(bk0[1], (Bp) + (wn + 1 * 16 + l16) * 64 + ((quad) ^ sw) * 8);          \
    DSR(bk0[2], (Bp) + (wn + 2 * 16 + l16) * 64 + ((quad) ^ sw) * 8);          \
    DSR(bk0[3], (Bp) + (wn + 3 * 16 + l16) * 64 + ((quad) ^ sw) * 8);
#define RD_BF1(Bp)                                                             \
    DSR(bk1[0], (Bp) + (wn + 0 * 16 + l16) * 64 + ((4 + quad) ^ sw) * 8);      \
    DSR(bk1[1], (Bp) + (wn + 1 * 16 + l16) * 64 + ((4 + quad) ^ sw) * 8);      \
    DSR(bk1[2], (Bp) + (wn + 2 * 16 + l16) * 64 + ((4 + quad) ^ sw) * 8);      \
    DSR(bk1[3], (Bp) + (wn + 3 * 16 + l16) * 64 + ((4 + quad) ^ sw) * 8);

// A-fragment group P: rows 2P*16 and (2P+1)*16, both ks halves (4 reads)
#define RD_A(P, Ap, rA, rB)                                                    \
    DSR(rA[0], (Ap) + (wm + (2 * (P)) * 16 + l16) * 64 + ((quad) ^ sw) * 8);   \
    DSR(rB[0], (Ap) + (wm + (2 * (P) + 1) * 16 + l16) * 64 + ((quad) ^ sw) * 8); \
    DSR(rA[1], (Ap) + (wm + (2 * (P)) * 16 + l16) * 64 + ((4 + quad) ^ sw) * 8); \
    DSR(rB[1], (Ap) + (wm + (2 * (P) + 1) * 16 + l16) * 64 + ((4 + quad) ^ sw) * 8);

// half-cluster: 8 MFMA, sched_barrier-fenced (rule 18)
#define CH(P, ks, rA, rB)                                                      \
    __builtin_amdgcn_sched_barrier(0);                                         \
    __builtin_amdgcn_s_setprio(1);                                             \
    _Pragma("unroll")                                                          \
    for (int ni = 0; ni < 4; ni++) {                                           \
        acc[2 * (P)][ni] = __builtin_amdgcn_mfma_f32_16x16x32_bf16(            \
            rA[ks], bk##ks[ni], acc[2 * (P)][ni], 0, 0, 0);                    \
        acc[2 * (P) + 1][ni] = __builtin_amdgcn_mfma_f32_16x16x32_bf16(        \
            rB[ks], bk##ks[ni], acc[2 * (P) + 1][ni], 0, 0, 0);                \
    }                                                                          \
    __builtin_amdgcn_s_setprio(0);                                             \
    __builtin_amdgcn_sched_barrier(0);

#define GEMM8P_KLOOP()                                                         \
    const int JT = K >> 6;                                                     \
    short8 bk0[4], bk1[4];                                                     \
    short8 aA0[2], aB0[2], aA1[2], aB1[2];                                     \
    short8 aA2[2], aB2[2], aA3[2], aB3[2];                                     \
    {   /* software-pipeline prologue: tile 0 reads + its C0 clusters */       \
        const u16* Ac = &aLds[0][0];                                           \
        const u16* Bc = &bLds[0][0];                                           \
        RD_BF0(Bc) RD_BF1(Bc)                                                  \
        RD_A(0, Ac, aA0, aB0)                                                  \
        RD_A(1, Ac, aA1, aB1)                                                  \
        asm volatile("s_waitcnt lgkmcnt(4)" ::: "memory");                     \
        CH(0, 0, aA0, aB0)                                                     \
        CH(0, 1, aA0, aB0)                                                     \
    }                                                                          \
    for (int j = 0; j < JT; ++j) {                                             \
        const int cur = j & 1, nb = cur ^ 1;                                   \
        const int jn1 = (j + 1 < JT) ? j + 1 : JT - 1;                         \
        const int jn2 = (j + 2 < JT) ? j + 2 : JT - 1;                         \
        const u16* Ac = &aLds[cur][0];                                         \
        const u16* An = &aLds[nb][0];                                          \
        const u16* Bn = &bLds[nb][0];                                          \
        RD_A(2, Ac, aA2, aB2)                                                  \
        stageA(jn1, 0, nb);                                                    \
        asm volatile("s_waitcnt lgkmcnt(4)" ::: "memory");  /* a1 ready */     \
        CH(1, 0, aA1, aB1)                                                     \
        CH(1, 1, aA1, aB1)  /* a2 drains under C1 */                           \
        RD_A(3, Ac, aA3, aB3)                                                  \
        stageA(jn1, 1, nb);                                                    \
        asm volatile("s_waitcnt lgkmcnt(4)" ::: "memory");  /* a2 ready */     \
        __builtin_amdgcn_s_barrier();  /* MID: bk reads done everywhere */     \
        stageB(jn2, 0, cur);                                                   \
        CH(2, 0, aA2, aB2)                                                     \
        CH(2, 1, aA2, aB2)  /* a3 drains under C2 */                           \
        stageB(jn2, 1, cur);                                                   \
        asm volatile("s_waitcnt lgkmcnt(0)" ::: "memory");  /* a3 ready */     \
        CH(3, 0, aA3, aB3)  /* bk0 dies */                                     \
        asm volatile("s_waitcnt vmcnt(4)" ::: "memory");                       \
        __builtin_amdgcn_s_barrier();  /* END: A(j+1),B(j+1) visible */        \
        if (j + 1 < JT) {                                                      \
            RD_BF0(Bn)                                                         \
            RD_A(0, An, aA0, aB0)                                              \
        }                                                                      \
        CH(3, 1, aA3, aB3)  /* bk1 dies; covers bf0'+a0' */                    \
        if (j + 1 < JT) {                                                      \
            asm volatile("s_waitcnt lgkmcnt(0)" ::: "memory");                 \
            RD_BF1(Bn)                                                         \
            RD_A(1, An, aA1, aB1)                                              \
            CH(0, 0, aA0, aB0)  /* next tile's C0 ks0; covers bf1' */          \
            asm volatile("s_waitcnt lgkmcnt(4)" ::: "memory");                 \
            CH(0, 1, aA0, aB0)  /* a1' drains under this + next C1 */          \
        }                                                                      \
    }                                                                          \
    asm volatile("s_waitcnt vmcnt(0)" ::: "memory");

// ---------------------------------------------------------------------------
// QKV projection, v6, fused RoPE epilogue. Writes q[n][h][l][64]
// (x0.125 folded), k[n][l][64], V transposed vt[n][d][l].
// Tail blocks (blockIdx.x >= nwgg) convert w_dense fp32->bf16 on the CUs
// idle during the 152-block GEMM (gemm_dense runs 2 dispatches later).
// ---------------------------------------------------------------------------
__global__ __launch_bounds__(512, 2) void gemm_qkv_8p(
    const u16* __restrict__ A, const u16* __restrict__ B,
    u16* __restrict__ qb, u16* __restrict__ kb, u16* __restrict__ vt,
    int M, int N, int K, int nt,
    const float* __restrict__ cvt_src, u16* __restrict__ cvt_dst, long cvt_n) {
    __shared__ __align__(16) u16 aLds[2][256 * 64];
    __shared__ __align__(16) u16 bLds[2][256 * 64];
    const int nwgg = (M >> 8) * nt;
    if ((int)blockIdx.x >= nwgg) {
        const long blockbase = (long)((int)blockIdx.x - nwgg) * 16384;
#pragma unroll
        for (int u = 0; u < 4; u++) {
            const long i = blockbase + (long)u * 4096 + (long)threadIdx.x * 8;
            if (i < cvt_n) cvt8_f32_bf16(cvt_src + i, cvt_dst + i);
        }
        return;
    }
    GEMM8P_PROLOGUE()
    GEMM8P_KLOOP()

    // ---- fused RoPE epilogue (C/D: col=l16, row=quad*4+r) ----
#pragma unroll
    for (int ni = 0; ni < 4; ni++) {
        const int c = n0 + wn + ni * 16 + l16;
        if (c >= N) continue;
        const int hh = c >> 6;
        const int d  = c & 63;
        float inv = 0.f;
        if (hh < 72) inv = expf((float)(2 * (d & 31)) * (-0.14391156831212787f));
#pragma unroll
        for (int mi = 0; mi < 8; mi++) {
#pragma unroll
            for (int r = 0; r < 4; r++) {
                const int row = m0 + wm + mi * 16 + quad * 4 + r;   // token
                const int tn = row >> 10;
                const int tl = row & 1023;
                float val = acc[mi][ni][r];
                if (hh < 72) {
                    float sv, cv;
                    sincosf((float)tl * inv, &sv, &cv);
                    const float pacc = acc[mi][ni ^ 2][r];          // col c^32
                    val = val * cv + ((d < 32) ? -pacc : pacc) * sv;
                }
                if (hh < 71) {
                    qb[((long)((tn * 71 + hh) * 1024 + tl)) * 64 + d] = f2bf(val * 0.125f);
                } else if (hh == 71) {
                    kb[((long)(tn * 1024 + tl)) * 64 + d] = f2bf(val);
                } else {
                    vt[((long)(tn * 64 + d)) * 1024 + tl] = f2bf(val);  // V^T
                }
            }
        }
    }
}

// ---------------------------------------------------------------------------
// Dense projection, v6: C_fp32[M,N] = A_bf16[M,K]*B_bf16[N,K]^T.
// ---------------------------------------------------------------------------
__global__ __launch_bounds__(512, 2) void gemm_dense_8p(
    const u16* __restrict__ A, const u16* __restrict__ B,
    float* __restrict__ C, int M, int N, int K, int nt) {
    __shared__ __align__(16) u16 aLds[2][256 * 64];
    __shared__ __align__(16) u16 bLds[2][256 * 64];
    const int nwgg = (M >> 8) * nt;
    GEMM8P_PROLOGUE()
    GEMM8P_KLOOP()

#pragma unroll
    for (int ni = 0; ni < 4; ni++) {
        const int col = n0 + wn + ni * 16 + l16;
        if (col >= N) continue;
#pragma unroll
        for (int mi = 0; mi < 8; mi++) {
#pragma unroll
            for (int r = 0; r < 4; r++) {
                const int row = m0 + wm + mi * 16 + quad * 4 + r;
                C[(long)row * N + col] = acc[mi][ni][r];
            }
        }
    }
}

// ---------------------------------------------------------------------------
// Flash-style MQA causal attention v2 (unchanged this round).
// ---------------------------------------------------------------------------
__global__ __launch_bounds__(256) void attn_kernel2(const u16* __restrict__ qb,
                                                    const u16* __restrict__ kb,
                                                    const u16* __restrict__ vt,
                                                    u16* __restrict__ ao) {
    __shared__ __align__(16) u16 k_lds[2][64 * 72];
    __shared__ __align__(16) u16 v_lds[2][64 * 72];
    __shared__ __align__(16) u16 p_lds[4][16 * 72];
    const int qt2 = blockIdx.x;
    const int h   = blockIdx.y;
    const int n   = blockIdx.z;
    const int t    = threadIdx.x;
    const int w    = t >> 6;
    const int lane = t & 63;
    const int quad = lane >> 4;
    const int l16  = lane & 15;
    const int Q0 = qt2 * 128;

    short8 aq[2][2];
#pragma unroll
    for (int mf = 0; mf < 2; mf++) {
        const u16* qrow = qb +
            ((long)((n * 71 + h) * 1024 + Q0 + 64 * mf + w * 16 + l16)) * 64;
        aq[mf][0] = *(const short8*)(qrow + quad * 8);
        aq[mf][1] = *(const short8*)(qrow + 32 + quad * 8);
    }

    floatx4 o[2][4];
    float lst[2][4];
    const floatx4 zf4 = {0.f, 0.f, 0.f, 0.f};
#pragma unroll
    for (int mf = 0; mf < 2; mf++) {
#pragma unroll
        for (int i = 0; i < 4; i++) { o[mf][i] = zf4; lst[mf][i] = 0.f; }
    }

    const int srow = t >> 2;
    const int scol = (t & 3) * 16;
    const u16* kb_n = kb + (long)n * 1024 * 64;
    const u16* vt_n = vt + (long)n * 64 * 1024;
    u16* pw = p_lds[w];

    const int ktend = 2 * qt2 + 2;

    auto stage = [&](int kt, int b) {
        const u16* krow = kb_n + (long)(kt * 64 + srow) * 64 + scol;
        *(uint4*)(k_lds[b] + srow * 72 + scol)     = *(const uint4*)(krow);
        *(uint4*)(k_lds[b] + srow * 72 + scol + 8) = *(const uint4*)(krow + 8);
        const u16* vrow = vt_n + (long)srow * 1024 + kt * 64 + scol;
        *(uint4*)(v_lds[b] + srow * 72 + scol)     = *(const uint4*)(vrow);
        *(uint4*)(v_lds[b] + srow * 72 + scol + 8) = *(const uint4*)(vrow + 8);
    };

    stage(0, 0);
    for (int kt = 0; kt < ktend; kt++) {
        const int buf = kt & 1;
        __syncthreads();
        if (kt + 1 < ktend) stage(kt + 1, 1 - buf);

#pragma unroll
        for (int mf = 0; mf < 2; mf++) {
            if (mf == 0 && kt == 2 * qt2 + 1) continue;
            floatx4 s[4];
#pragma unroll
            for (int sub = 0; sub < 4; sub++) {
                const short8 b0 = *(const short8*)(k_lds[buf] + (sub * 16 + l16) * 72 + quad * 8);
                const short8 b1 = *(const short8*)(k_lds[buf] + (sub * 16 + l16) * 72 + 32 + quad * 8);
                floatx4 z = zf4;
                z = __builtin_amdgcn_mfma_f32_16x16x32_bf16(aq[mf][0], b0, z, 0, 0, 0);
                z = __builtin_amdgcn_mfma_f32_16x16x32_bf16(aq[mf][1], b1, z, 0, 0, 0);
                s[sub] = z;
            }
            const bool diag = (kt == 2 * qt2 + mf);
            const int rowb = Q0 + 64 * mf + w * 16 + quad * 4;
#pragma unroll
            for (int sub = 0; sub < 4; sub++) {
                const int key = kt * 64 + sub * 16 + l16;
#pragma unroll
                for (int r = 0; r < 4; r++) {
                    float p = __expf(s[sub][r]);
                    if (diag && key > rowb + r) p = 0.f;
                    lst[mf][r] += p;
                    pw[(quad * 4 + r) * 72 + sub * 16 + l16] = f2bf(p);
                }
            }
            const short8 ap0 = *(const short8*)(pw + l16 * 72 + quad * 8);
            const short8 ap1 = *(const short8*)(pw + l16 * 72 + 32 + quad * 8);
#pragma unroll
            for (int dch = 0; dch < 4; dch++) {
                const short8 bv0 = *(const short8*)(v_lds[buf] + (dch * 16 + l16) * 72 + quad * 8);
                const short8 bv1 = *(const short8*)(v_lds[buf] + (dch * 16 + l16) * 72 + 32 + quad * 8);
                o[mf][dch] = __builtin_amdgcn_mfma_f32_16x16x32_bf16(ap0, bv0, o[mf][dch], 0, 0, 0);
                o[mf][dch] = __builtin_amdgcn_mfma_f32_16x16x32_bf16(ap1, bv1, o[mf][dch], 0, 0, 0);
            }
        }
    }

    float lsum[2][4];
#pragma unroll
    for (int mf = 0; mf < 2; mf++) {
#pragma unroll
        for (int r = 0; r < 4; r++) {
            float v = lst[mf][r];
#pragma unroll
            for (int mk = 1; mk < 16; mk <<= 1) v += __shfl_xor(v, mk, 64);
            lsum[mf][r] = v;
        }
    }
#pragma unroll
    for (int mf = 0; mf < 2; mf++) {
#pragma unroll
        for (int dch = 0; dch < 4; dch++) {
#pragma unroll
            for (int r = 0; r < 4; r++) {
                const float val = o[mf][dch][r] / lsum[mf][r];
                const int row = n * 1024 + Q0 + 64 * mf + w * 16 + quad * 4 + r;
                const int col = h * 64 + dch * 16 + l16;
                ao[(long)row * 4544 + col] = f2bf(val);
            }
        }
    }
}

// ---------------------------------------------------------------------------
// Fallback path kernels (fp32 staging) — used only if ws too small.
// ---------------------------------------------------------------------------
__global__ __launch_bounds__(256) void gemm_qkv_f32(const float* __restrict__ A,
                                                    const float* __restrict__ B,
                                                    u16* __restrict__ qb,
                                                    u16* __restrict__ kb,
                                                    u16* __restrict__ vt,
                                                    int M, int N, int K) {
    __shared__ __align__(16) u16 a_lds[128 * 32];
    __shared__ __align__(16) u16 b_lds[128 * 32];
    const int t    = threadIdx.x;
    const int lane = t & 63;
    const int w    = t >> 6;
    const int quad = lane >> 4;
    const int l16  = lane & 15;
    const int m0 = blockIdx.y * 128;
    const int n0 = blockIdx.x * 128;
    const int wm = (w >> 1) * 64;
    const int wn = (w & 1) * 64;
    const int srow = t >> 2;
    const int scol = (t & 3) * 8;
    const float* Ap0 = A + (long)(m0 + srow) * K + scol;
    const float* Ap1 = A + (long)(m0 + 64 + srow) * K + scol;
    int bn0 = n0 + srow;      if (bn0 >= N) bn0 = N - 1;
    int bn1 = n0 + 64 + srow; if (bn1 >= N) bn1 = N - 1;
    const float* Bp0 = B + (long)bn0 * K + scol;
    const float* Bp1 = B + (long)bn1 * K + scol;
    u16* as0 = a_lds + srow * 32 + scol;
    u16* as1 = a_lds + (64 + srow) * 32 + scol;
    u16* bs0 = b_lds + srow * 32 + scol;
    u16* bs1 = b_lds + (64 + srow) * 32 + scol;
    floatx4 acc[4][4];
    const floatx4 zf4 = {0.f, 0.f, 0.f, 0.f};
#pragma unroll
    for (int i = 0; i < 4; i++)
#pragma unroll
        for (int j = 0; j < 4; j++) acc[i][j] = zf4;
    for (int k0 = 0; k0 < K; k0 += 32) {
        cvt8_f32_bf16(Ap0 + k0, as0);
        cvt8_f32_bf16(Ap1 + k0, as1);
        cvt8_f32_bf16(Bp0 + k0, bs0);
        cvt8_f32_bf16(Bp1 + k0, bs1);
        __syncthreads();
        short8 af[4], bfr[4];
#pragma unroll
        for (int i = 0; i < 4; i++)
            af[i] = *(const short8*)(a_lds + (wm + i * 16 + l16) * 32 + quad * 8);
#pragma unroll
        for (int j = 0; j < 4; j++)
            bfr[j] = *(const short8*)(b_lds + (wn + j * 16 + l16) * 32 + quad * 8);
#pragma unroll
        for (int i = 0; i < 4; i++)
#pragma unroll
            for (int j = 0; j < 4; j++)
                acc[i][j] = __builtin_amdgcn_mfma_f32_16x16x32_bf16(af[i], bfr[j], acc[i][j], 0, 0, 0);
        __syncthreads();
    }
#pragma unroll
    for (int j = 0; j < 4; j++) {
        const int c = n0 + wn + j * 16 + l16;
        if (c >= N) continue;
        const int hh = c >> 6;
        const int d  = c & 63;
        float inv = 0.f;
        if (hh < 72) inv = expf((float)(2 * (d & 31)) * (-0.14391156831212787f));
#pragma unroll
        for (int i = 0; i < 4; i++) {
#pragma unroll
            for (int r = 0; r < 4; r++) {
                const int row = m0 + wm + i * 16 + quad * 4 + r;
                const int tn = row >> 10;
                const int tl = row & 1023;
                float val = acc[i][j][r];
                if (hh < 72) {
                    float sv, cv;
                    sincosf((float)tl * inv, &sv, &cv);
                    const float pacc = acc[i][j ^ 2][r];
                    val = val * cv + ((d < 32) ? -pacc : pacc) * sv;
                }
                if (hh < 71) {
                    qb[((long)((tn * 71 + hh) * 1024 + tl)) * 64 + d] = f2bf(val * 0.125f);
                } else if (hh == 71) {
                    kb[((long)(tn * 1024 + tl)) * 64 + d] = f2bf(val);
                } else {
                    vt[((long)(tn * 64 + d)) * 1024 + tl] = f2bf(val);
                }
            }
        }
    }
}

__global__ __launch_bounds__(256) void gemm_dense_f32(const u16* __restrict__ A,
                                                      const float* __restrict__ B,
                                                      float* __restrict__ C,
                                                      int M, int N, int K) {
    __shared__ __align__(16) u16 a_lds[128 * 32];
    __shared__ __align__(16) u16 b_lds[128 * 32];
    const int t    = threadIdx.x;
    const int lane = t & 63;
    const int w    = t >> 6;
    const int quad = lane >> 4;
    const int l16  = lane & 15;
    const int m0 = blockIdx.y * 128;
    const int n0 = blockIdx.x * 128;
    const int wm = (w >> 1) * 64;
    const int wn = (w & 1) * 64;
    const int srow = t >> 2;
    const int scol = (t & 3) * 8;
    const u16* Ap0 = A + (long)(m0 + srow) * K + scol;
    const u16* Ap1 = A + (long)(m0 + 64 + srow) * K + scol;
    int bn0 = n0 + srow;      if (bn0 >= N) bn0 = N - 1;
    int bn1 = n0 + 64 + srow; if (bn1 >= N) bn1 = N - 1;
    const float* Bp0 = B + (long)bn0 * K + scol;
    const float* Bp1 = B + (long)bn1 * K + scol;
    u16* as0 = a_lds + srow * 32 + scol;
    u16* as1 = a_lds + (64 + srow) * 32 + scol;
    u16* bs0 = b_lds + srow * 32 + scol;
    u16* bs1 = b_lds + (64 + srow) * 32 + scol;
    floatx4 acc[4][4];
    const floatx4 zf4 = {0.f, 0.f, 0.f, 0.f};
#pragma unroll
    for (int i = 0; i < 4; i++)
#pragma unroll
        for (int j = 0; j < 4; j++) acc[i][j] = zf4;
    for (int k0 = 0; k0 < K; k0 += 32) {
        *(uint4*)as0 = *(const uint4*)(Ap0 + k0);
        *(uint4*)as1 = *(const uint4*)(Ap1 + k0);
        cvt8_f32_bf16(Bp0 + k0, bs0);
        cvt8_f32_bf16(Bp1 + k0, bs1);
        __syncthreads();
        short8 af[4], bfr[4];
#pragma unroll
        for (int i = 0; i < 4; i++)
            af[i] = *(const short8*)(a_lds + (wm + i * 16 + l16) * 32 + quad * 8);
#pragma unroll
        for (int j = 0; j < 4; j++)
            bfr[j] = *(const short8*)(b_lds + (wn + j * 16 + l16) * 32 + quad * 8);
#pragma unroll
        for (int i = 0; i < 4; i++)
#pragma unroll
            for (int j = 0; j < 4; j++)
                acc[i][j] = __builtin_amdgcn_mfma_f32_16x16x32_bf16(af[i], bfr[j], acc[i][j], 0, 0, 0);
        __syncthreads();
    }
#pragma unroll
    for (int i = 0; i < 4; i++) {
#pragma unroll
        for (int j = 0; j < 4; j++) {
            const int col = n0 + wn + j * 16 + l16;
            if (col < N) {
#pragma unroll
                for (int r = 0; r < 4; r++) {
                    const int row = m0 + wm + i * 16 + quad * 4 + r;
                    C[(long)row * N + col] = acc[i][j][r];
                }
            }
        }
    }
}

// ---------------------------------------------------------------------------
extern "C" void kernel_launch(void* const* d_in, const int* in_sizes, int n_in,
                              void* d_out, int out_size, void* d_ws, size_t ws_size,
                              hipStream_t stream) {
    (void)in_sizes; (void)n_in; (void)out_size;
    const float* hidden  = (const float*)d_in[0];   // (2,1024,4544) fp32
    const float* w_qkv   = (const float*)d_in[1];   // (4672,4544)  fp32
    const float* w_dense = (const float*)d_in[2];   // (4544,4544)  fp32
    float* out = (float*)d_out;                     // (2,1024,4544) fp32

    const long N_HID = (long)2048 * 4544;
    const long N_QKV = (long)4672 * 4544;
    const long N_DEN = (long)4544 * 4544;
    const long N_Q   = (long)2 * 71 * 1024 * 64;
    const long N_KV  = (long)2 * 1024 * 64;
    const long N_AO  = (long)2048 * 4544;

    const size_t needA = (size_t)(N_HID + N_QKV + N_DEN + N_Q + 2 * N_KV + N_AO) * 2;

    if (ws_size >= needA) {
        // ---- Path A: bf16 pre-convert + pipelined 256^2 GEMMs ----
        u16* hid_bf  = (u16*)d_ws;
        u16* wqkv_bf = hid_bf + N_HID;
        u16* wden_bf = wqkv_bf + N_QKV;
        u16* qbuf    = wden_bf + N_DEN;
        u16* kbuf    = qbuf + N_Q;
        u16* vtbuf   = kbuf + N_KV;    // V^T: [n][64][1024]
        u16* aout    = vtbuf + N_KV;

        // hidden + w_qkv only (w_dense cvt folded into qkv dispatch tail)
        cvt3_kernel<<<dim3(10366, 2), 256, 0, stream>>>(
            hidden, hid_bf, N_HID, w_qkv, wqkv_bf, N_QKV, w_dense, wden_bf, N_DEN);
        // M=2048 (8 tiles), N=4672 (19 tiles), K=4544 (71 K-tiles)
        // + 1261 tail blocks converting w_dense (20,647,936 elems / 16384)
        gemm_qkv_8p<<<dim3(8 * 19 + 1261), 512, 0, stream>>>(
            hid_bf, wqkv_bf, qbuf, kbuf, vtbuf,
            2048, 4672, 4544, 19,
            w_dense, wden_bf, N_DEN);
        attn_kernel2<<<dim3(8, 71, 2), 256, 0, stream>>>(qbuf, kbuf, vtbuf, aout);
        // M=2048 (8 tiles), N=4544 (18 tiles)
        gemm_dense_8p<<<dim3(8 * 18), 512, 0, stream>>>(aout, wden_bf, out,
                                                        2048, 4544, 4544, 18);
    } else {
        // ---- Path B: fallback (fp32 staging conversion) ----
        u16* qbuf  = (u16*)d_ws;
        u16* kbuf  = qbuf + N_Q;
        u16* vtbuf = kbuf + N_KV;
        u16* aout  = vtbuf + N_KV;
        gemm_qkv_f32<<<dim3(37, 16), 256, 0, stream>>>(hidden, w_qkv,
                                                       qbuf, kbuf, vtbuf,
                                                       2048, 4672, 4544);
        attn_kernel2<<<dim3(8, 71, 2), 256, 0, stream>>>(qbuf, kbuf, vtbuf, aout);
        gemm_dense_f32<<<dim3(36, 16), 256, 0, stream>>>(aout, w_dense, out,
                                                         2048, 4544, 4544);
    }
}